// Round 1
// baseline (1919.052 us; speedup 1.0000x reference)
//
#include <hip/hip_runtime.h>

#define S_TOT 2304
#define D_TOT 3072
#define NH    24
#define HD    128
#define BLK_R 2048
#define TIP   128
#define DIP   4096

typedef __attribute__((ext_vector_type(4))) float f4;
typedef __attribute__((ext_vector_type(8))) short bh8;
typedef unsigned short u16;
typedef unsigned int   u32;
typedef unsigned long long u64;

__device__ __forceinline__ u16 f2bf(float f) {
    u32 u = __float_as_uint(f);
    u32 r = (u + 0x7fffu + ((u >> 16) & 1u)) >> 16;
    return (u16)r;
}
__device__ __forceinline__ uint4 pack8u(float4 a, float4 b) {
    uint4 u;
    u.x = (u32)f2bf(a.x) | ((u32)f2bf(a.y) << 16);
    u.y = (u32)f2bf(a.z) | ((u32)f2bf(a.w) << 16);
    u.z = (u32)f2bf(b.x) | ((u32)f2bf(b.y) << 16);
    u.w = (u32)f2bf(b.z) | ((u32)f2bf(b.w) << 16);
    return u;
}
__device__ __forceinline__ bh8 pack8v(float4 a, float4 b) {
    bh8 v;
    v[0] = (short)f2bf(a.x); v[1] = (short)f2bf(a.y);
    v[2] = (short)f2bf(a.z); v[3] = (short)f2bf(a.w);
    v[4] = (short)f2bf(b.x); v[5] = (short)f2bf(b.y);
    v[6] = (short)f2bf(b.z); v[7] = (short)f2bf(b.w);
    return v;
}

// ---------------- GEMM: C[M][N] (+)= A[M][K] @ B[N][K]^T + bias ----------------
// A, B, bias f32 (converted to bf16 during LDS staging); C f32.
// 128x128 tile, BK=64, 4 waves (2x2), 4x4 mfma 16x16x32 each.
// mode 0: store (+bias). mode 1: C += (single writer). mode 2: atomicAdd (split-K, C pre-zeroed).
__global__ __launch_bounds__(256)
void gemm_f32(const float* __restrict__ A, const float* __restrict__ B,
              const float* __restrict__ bias, float* __restrict__ C,
              int M, int N, int K, int mode, int ksplit)
{
    __shared__ u16 As[128 * 64];
    __shared__ u16 Bs[128 * 64];
    const int tid  = threadIdx.x;
    const int wv   = tid >> 6;
    const int lane = tid & 63;
    const int quad = lane >> 4;
    const int l16  = lane & 15;
    const int wm   = (wv >> 1) << 6;
    const int wn   = (wv & 1) << 6;
    const int m0   = blockIdx.x << 7;
    const int n0   = blockIdx.y << 7;
    const int kch  = K / ksplit;
    const int kbeg = blockIdx.z * kch;
    const int kend = kbeg + kch;

    f4 acc[4][4] = {};

    for (int k0 = kbeg; k0 < kend; k0 += 64) {
#pragma unroll
        for (int p = 0; p < 4; ++p) {
            int idx = (p << 11) + (tid << 3);
            int r = idx >> 6, c = idx & 63;
            const float* ap = A + (size_t)(m0 + r) * K + k0 + c;
            *(uint4*)(&As[idx]) = pack8u(*(const float4*)ap, *(const float4*)(ap + 4));
            const float* bp = B + (size_t)(n0 + r) * K + k0 + c;
            *(uint4*)(&Bs[idx]) = pack8u(*(const float4*)bp, *(const float4*)(bp + 4));
        }
        __syncthreads();
#pragma unroll
        for (int kk = 0; kk < 2; ++kk) {
            bh8 a[4], b[4];
#pragma unroll
            for (int i = 0; i < 4; ++i)
                a[i] = *(const bh8*)(&As[(wm + (i << 4) + l16) * 64 + (kk << 5) + (quad << 3)]);
#pragma unroll
            for (int i = 0; i < 4; ++i)
                b[i] = *(const bh8*)(&Bs[(wn + (i << 4) + l16) * 64 + (kk << 5) + (quad << 3)]);
#pragma unroll
            for (int mt = 0; mt < 4; ++mt)
#pragma unroll
                for (int nt = 0; nt < 4; ++nt)
                    acc[mt][nt] = __builtin_amdgcn_mfma_f32_16x16x32_bf16(a[mt], b[nt], acc[mt][nt], 0, 0, 0);
        }
        __syncthreads();
    }
#pragma unroll
    for (int mt = 0; mt < 4; ++mt) {
#pragma unroll
        for (int nt = 0; nt < 4; ++nt) {
            int n = n0 + wn + (nt << 4) + l16;
            float bs = bias ? bias[n] : 0.0f;
#pragma unroll
            for (int r = 0; r < 4; ++r) {
                int m = m0 + wm + (mt << 4) + (quad << 2) + r;
                size_t o = (size_t)m * N + n;
                float v = acc[mt][nt][r] + bs;
                if (mode == 0)      C[o] = v;
                else if (mode == 1) C[o] += v;
                else                atomicAdd(&C[o], v);
            }
        }
    }
}

// ---------------- LoRA down: T1[s][r] = sum_d X[2048+s][d]*Dwn[r][d], f32 out ----------------
__global__ __launch_bounds__(256)
void lora_down_k(const float* __restrict__ X, const float* __restrict__ Dwn, float* __restrict__ T1)
{
    int wv = threadIdx.x >> 6, lane = threadIdx.x & 63;
    int quad = lane >> 4, l16 = lane & 15;
    int gw = blockIdx.x * 4 + wv;          // 0..127
    int mt = gw >> 3, nt = gw & 7;
    const float* ap = X + (size_t)(BLK_R + (mt << 4) + l16) * D_TOT + (quad << 3);
    const float* bp = Dwn + (size_t)((nt << 4) + l16) * D_TOT + (quad << 3);
    f4 acc = {};
    for (int c = 0; c < 96; ++c) {
        bh8 a = pack8v(*(const float4*)(ap + (c << 5)), *(const float4*)(ap + (c << 5) + 4));
        bh8 b = pack8v(*(const float4*)(bp + (c << 5)), *(const float4*)(bp + (c << 5) + 4));
        acc = __builtin_amdgcn_mfma_f32_16x16x32_bf16(a, b, acc, 0, 0, 0);
    }
#pragma unroll
    for (int r = 0; r < 4; ++r) {
        int s  = (mt << 4) + (quad << 2) + r;
        int rr = (nt << 4) + l16;
        T1[(size_t)s * 128 + rr] = acc[r];
    }
}

// ---------------- RMSNorm (+f32 weight) + optional RoPE; f32 [Slen][3072] -> bf16 [H][Slen][128]
template <int ROPE>
__global__ __launch_bounds__(256)
void norm_rope_k(const float* __restrict__ X, const float* __restrict__ w,
                 const float* __restrict__ ct, const float* __restrict__ st,
                 u16* __restrict__ Out, int Slen)
{
    int g = blockIdx.x * 4 + (threadIdx.x >> 6);
    int lane = threadIdx.x & 63;
    int s = g / NH, h = g % NH;
    const float* xp = X + (size_t)s * D_TOT + (h << 7) + (lane << 1);
    float2 xv = *(const float2*)xp;
    float ss = xv.x * xv.x + xv.y * xv.y;
#pragma unroll
    for (int off = 1; off <= 32; off <<= 1) ss += __shfl_xor(ss, off);
    float invr = rsqrtf(ss * (1.0f / 128.0f) + 1e-5f);
    float a = xv.x * invr, b = xv.y * invr;
    if (w) { a *= w[lane << 1]; b *= w[(lane << 1) + 1]; }
    float o0 = a, o1 = b;
    if (ROPE) {
        float c0 = ct[(size_t)s * HD + (lane << 1)], c1 = ct[(size_t)s * HD + (lane << 1) + 1];
        float n0 = st[(size_t)s * HD + (lane << 1)], n1 = st[(size_t)s * HD + (lane << 1) + 1];
        o0 = a * c0 - b * n0;
        o1 = b * c1 + a * n1;
    }
    size_t oo = ((size_t)h * Slen + s) * HD + (lane << 1);
    u32 pack = (u32)f2bf(o0) | ((u32)f2bf(o1) << 16);
    *(u32*)(&Out[oo]) = pack;
}

// ---------------- V transpose: f32 [Slen][3072] -> bf16 Vt[H][HD][Slen] ----------------
__global__ __launch_bounds__(256)
void transpose_v_k(const float* __restrict__ V, u16* __restrict__ Vt, int Slen)
{
    __shared__ u16 tile[64][130];
    int h = blockIdx.y;
    int s0 = blockIdx.x << 6;
    int tid = threadIdx.x;
#pragma unroll
    for (int p = 0; p < 32; ++p) {
        int flat = (p << 8) + tid;
        int si = flat >> 7, d = flat & 127;
        tile[si][d] = f2bf(V[(size_t)(s0 + si) * D_TOT + (h << 7) + d]);
    }
    __syncthreads();
#pragma unroll
    for (int p = 0; p < 32; ++p) {
        int flat = (p << 8) + tid;
        int d = flat >> 6, si = flat & 63;
        Vt[((size_t)(h << 7) + d) * Slen + s0 + si] = tile[si][d];
    }
}

// ---------------- MFMA flash attention (per-wave 16 q-rows, 32-key tiles) ----------------
// Qb [H][S_TOT][128], Kb [H][Lk][128], Vt [H][128][Lk]; Out f32 [S_TOT][3072].
// Q rows >= 2048 start at key tile cond_start (64 for main attn, 0 for IP). accum=1 RMWs Out.
// R2: K ping-pong register prefetch, early V loads, deferred l-sum reduction (per-lane
// partial; alpha is row-uniform), skip-rescale when tile max doesn't grow, setprio on MFMA.
// NOTE: key-tile counts must be even (72, 8, 4 here) for the unroll-2 pipeline.
__global__ __launch_bounds__(256, 3)
void attn_k(const u16* __restrict__ Qb, const u16* __restrict__ Kb,
            const u16* __restrict__ Vt, float* __restrict__ Out,
            int Lk, int cond_start, int accum)
{
    __shared__ u16 Pl[4][16 * 40];   // per-wave P tile, rows padded to 40
    const int h = blockIdx.y;
    const int qt = blockIdx.x;
    const int wv = threadIdx.x >> 6;
    const int lane = threadIdx.x & 63;
    const int quad = lane >> 4, l16 = lane & 15;
    const int sb = (qt << 6) + (wv << 4);
    const float sc2 = 0.08838834764831845f * 1.4426950408889634f;  // 1/sqrt(128) * log2(e)

    bh8 qf[4];
    const u16* qp = Qb + ((size_t)h * S_TOT + sb + l16) * HD + (quad << 3);
#pragma unroll
    for (int c = 0; c < 4; ++c) qf[c] = *(const bh8*)(qp + (c << 5));

    f4 o[8] = {};
    float mrow[4] = {-1e30f, -1e30f, -1e30f, -1e30f};
    float lpart[4] = {0.f, 0.f, 0.f, 0.f};   // per-lane partial row sum (reduced after loop)
    u16* pl = &Pl[wv][0];

    const int kt0 = (sb >= BLK_R) ? cond_start : 0;
    const int ktN = Lk >> 5;

    const u16* kbase = Kb + ((size_t)h * Lk + l16) * HD + (quad << 3);
    const u16* vbase = Vt + ((size_t)(h << 7) + l16) * Lk + (quad << 3);

    bh8 ka[8], kb2[8], vv[8];

    auto loadK = [&](int kt, bh8* dst) {
        const u16* kp = kbase + ((size_t)kt << 5) * HD;
#pragma unroll
        for (int c = 0; c < 4; ++c) {
            dst[c]     = *(const bh8*)(kp + (c << 5));
            dst[4 + c] = *(const bh8*)(kp + 2048 + (c << 5));   // +16 key rows * 128
        }
    };

    auto body = [&](int kt, bh8* cur, bh8* nxt) {
        // prefetch next K tile (clamped re-load on last iter: valid mem, unused result)
        int ktn = (kt + 1 < ktN) ? kt + 1 : kt;
        loadK(ktn, nxt);
        // V loads for this tile issued early: hidden under QK + softmax
        {
            const u16* vp = vbase + ((size_t)kt << 5);
#pragma unroll
            for (int dt = 0; dt < 8; ++dt)
                vv[dt] = *(const bh8*)(vp + ((size_t)dt << 4) * Lk);
        }
        f4 s0 = {}, s1 = {};
        __builtin_amdgcn_s_setprio(1);
#pragma unroll
        for (int c = 0; c < 4; ++c) {
            s0 = __builtin_amdgcn_mfma_f32_16x16x32_bf16(qf[c], cur[c],     s0, 0, 0, 0);
            s1 = __builtin_amdgcn_mfma_f32_16x16x32_bf16(qf[c], cur[4 + c], s1, 0, 0, 0);
        }
        __builtin_amdgcn_s_setprio(0);
        float mx[4];
#pragma unroll
        for (int r = 0; r < 4; ++r) {
            s0[r] *= sc2; s1[r] *= sc2;
            mx[r] = fmaxf(s0[r], s1[r]);
        }
#pragma unroll
        for (int off = 1; off <= 8; off <<= 1)
#pragma unroll
            for (int r = 0; r < 4; ++r) mx[r] = fmaxf(mx[r], __shfl_xor(mx[r], off));
        // rescale only when the running max actually grew (wave-uniform branch)
        int grow = 0;
#pragma unroll
        for (int r = 0; r < 4; ++r) grow |= (mx[r] > mrow[r]) ? 1 : 0;
        if (__any(grow)) {
#pragma unroll
            for (int r = 0; r < 4; ++r) {
                float mn = fmaxf(mrow[r], mx[r]);
                float al = exp2f(mrow[r] - mn);
                mrow[r] = mn;
                lpart[r] *= al;
#pragma unroll
                for (int dt = 0; dt < 8; ++dt) o[dt][r] *= al;
            }
        }
        float p0[4], p1[4];
#pragma unroll
        for (int r = 0; r < 4; ++r) {
            p0[r] = exp2f(s0[r] - mrow[r]);
            p1[r] = exp2f(s1[r] - mrow[r]);
            lpart[r] += p0[r] + p1[r];     // per-lane partial; cross-lane reduce after loop
        }
        // P (C-layout) -> LDS -> A-layout (wave-internal, lgkmcnt-ordered)
#pragma unroll
        for (int r = 0; r < 4; ++r) {
            pl[((quad << 2) + r) * 40 + l16]      = f2bf(p0[r]);
            pl[((quad << 2) + r) * 40 + 16 + l16] = f2bf(p1[r]);
        }
        bh8 pa = *(const bh8*)(pl + l16 * 40 + (quad << 3));
        __builtin_amdgcn_s_setprio(1);
#pragma unroll
        for (int dt = 0; dt < 8; ++dt)
            o[dt] = __builtin_amdgcn_mfma_f32_16x16x32_bf16(pa, vv[dt], o[dt], 0, 0, 0);
        __builtin_amdgcn_s_setprio(0);
    };

    loadK(kt0, ka);
    for (int kt = kt0; kt + 1 < ktN; kt += 2) {
        body(kt, ka, kb2);
        body(kt + 1, kb2, ka);
    }

    // final cross-lane row-sum reduction (once, instead of per tile)
#pragma unroll
    for (int off = 1; off <= 8; off <<= 1)
#pragma unroll
        for (int r = 0; r < 4; ++r) lpart[r] += __shfl_xor(lpart[r], off);
    float inv[4];
#pragma unroll
    for (int r = 0; r < 4; ++r) inv[r] = 1.0f / lpart[r];
#pragma unroll
    for (int dt = 0; dt < 8; ++dt) {
#pragma unroll
        for (int r = 0; r < 4; ++r) {
            int row = sb + (quad << 2) + r;
            int col = (h << 7) + (dt << 4) + l16;
            size_t idx = (size_t)row * D_TOT + col;
            float v = o[dt][r] * inv[r];
            if (accum) v += Out[idx];
            Out[idx] = v;
        }
    }
}

// ---------------- workspace layout (byte offsets), total ~132.5 MB (ws >= 215 MB verified R1) ----
static const u64 B_QF   = 0;           // fp32 [2304][3072]
static const u64 B_KF   = 28311552;
static const u64 B_VF   = 56623104;
static const u64 B_KIPF = 84934656;    // fp32 [128][3072]
static const u64 B_VIPF = 86507520;
static const u64 B_T1   = 88080384;    // fp32 [3][256][128]
static const u64 B_QB   = 88473600;    // bf16 [24][2304][128]
static const u64 B_KB   = 102629376;
static const u64 B_VT   = 116785152;   // bf16 [24][128][2304]
static const u64 B_KIPB = 130940928;   // bf16 [24][128][128]
static const u64 B_VIPT = 131727360;   // bf16 [24][128][128]

extern "C" void kernel_launch(void* const* d_in, const int* in_sizes, int n_in,
                              void* d_out, int out_size, void* d_ws, size_t ws_size,
                              hipStream_t stream) {
    (void)in_sizes; (void)n_in; (void)out_size; (void)ws_size;
    const float* x    = (const float*)d_in[0];
    const float* img  = (const float*)d_in[1];
    const float* rc   = (const float*)d_in[2];
    const float* rsn  = (const float*)d_in[3];
    const float* Wq   = (const float*)d_in[4];
    const float* bq   = (const float*)d_in[5];
    const float* Wk   = (const float*)d_in[6];
    const float* bk   = (const float*)d_in[7];
    const float* Wv   = (const float*)d_in[8];
    const float* bv   = (const float*)d_in[9];
    const float* qdn  = (const float*)d_in[10];
    const float* qup  = (const float*)d_in[11];
    const float* kdn  = (const float*)d_in[12];
    const float* kup  = (const float*)d_in[13];
    const float* vdn  = (const float*)d_in[14];
    const float* vup  = (const float*)d_in[15];
    const float* nqw  = (const float*)d_in[16];
    const float* nkw  = (const float*)d_in[17];
    const float* Wkip = (const float*)d_in[18];
    const float* Wvip = (const float*)d_in[19];

    float* qf   = (float*)((char*)d_ws + B_QF);
    float* kf   = (float*)((char*)d_ws + B_KF);
    float* vf   = (float*)((char*)d_ws + B_VF);
    float* kipf = (float*)((char*)d_ws + B_KIPF);
    float* vipf = (float*)((char*)d_ws + B_VIPF);
    float* t1   = (float*)((char*)d_ws + B_T1);
    u16*   Qb   = (u16*)((char*)d_ws + B_QB);
    u16*   Kb   = (u16*)((char*)d_ws + B_KB);
    u16*   Vt   = (u16*)((char*)d_ws + B_VT);
    u16*   Kipb = (u16*)((char*)d_ws + B_KIPB);
    u16*   Vipt = (u16*)((char*)d_ws + B_VIPT);
    float* outf = (float*)d_out;

    // zero the split-K atomic accumulation targets
    hipMemsetAsync((char*)d_ws + B_KIPF, 0, 2 * 1572864, stream);

    // 1) QKV projections: [2304][3072] = x @ W^T + bias (fp32 out)
    gemm_f32<<<dim3(18, 24, 1), dim3(256), 0, stream>>>(x, Wq, bq, qf, S_TOT, D_TOT, D_TOT, 0, 1);
    gemm_f32<<<dim3(18, 24, 1), dim3(256), 0, stream>>>(x, Wk, bk, kf, S_TOT, D_TOT, D_TOT, 0, 1);
    gemm_f32<<<dim3(18, 24, 1), dim3(256), 0, stream>>>(x, Wv, bv, vf, S_TOT, D_TOT, D_TOT, 0, 1);

    // 2) LoRA: down (t1 = x_cond @ down^T), then up (+= into rows 2048..2303)
    lora_down_k<<<dim3(32), dim3(256), 0, stream>>>(x, qdn, t1);
    lora_down_k<<<dim3(32), dim3(256), 0, stream>>>(x, kdn, t1 + 32768);
    lora_down_k<<<dim3(32), dim3(256), 0, stream>>>(x, vdn, t1 + 65536);
    gemm_f32<<<dim3(2, 24, 1), dim3(256), 0, stream>>>(t1,         qup, nullptr, qf + (size_t)BLK_R * D_TOT, 256, D_TOT, 128, 1, 1);
    gemm_f32<<<dim3(2, 24, 1), dim3(256), 0, stream>>>(t1 + 32768, kup, nullptr, kf + (size_t)BLK_R * D_TOT, 256, D_TOT, 128, 1, 1);
    gemm_f32<<<dim3(2, 24, 1), dim3(256), 0, stream>>>(t1 + 65536, vup, nullptr, vf + (size_t)BLK_R * D_TOT, 256, D_TOT, 128, 1, 1);

    // 3) IP projections: [128][3072] = img @ W_ip^T (split-K=8, atomic into zeroed fp32)
    gemm_f32<<<dim3(1, 24, 8), dim3(256), 0, stream>>>(img, Wkip, nullptr, kipf, TIP, D_TOT, DIP, 2, 8);
    gemm_f32<<<dim3(1, 24, 8), dim3(256), 0, stream>>>(img, Wvip, nullptr, vipf, TIP, D_TOT, DIP, 2, 8);

    // 4) norm (+rope) -> head-major bf16; V transposes
    norm_rope_k<1><<<dim3(13824), dim3(256), 0, stream>>>(qf, nqw, rc, rsn, Qb, S_TOT);
    norm_rope_k<1><<<dim3(13824), dim3(256), 0, stream>>>(kf, nkw, rc, rsn, Kb, S_TOT);
    norm_rope_k<0><<<dim3(768),   dim3(256), 0, stream>>>(kipf, nullptr, nullptr, nullptr, Kipb, TIP);
    transpose_v_k<<<dim3(36, 24), dim3(256), 0, stream>>>(vf, Vt, S_TOT);
    transpose_v_k<<<dim3(2, 24),  dim3(256), 0, stream>>>(vipf, Vipt, TIP);

    // 5) attention: main writes f32 out; IP attention accumulates (RMW)
    attn_k<<<dim3(36, 24), dim3(256), 0, stream>>>(Qb, Kb,   Vt,   outf, S_TOT, 64, 0);
    attn_k<<<dim3(36, 24), dim3(256), 0, stream>>>(Qb, Kipb, Vipt, outf, TIP,   0,  1);
}

// Round 2
// 1752.022 us; speedup vs baseline: 1.0953x; 1.0953x over previous
//
#include <hip/hip_runtime.h>

#define S_TOT 2304
#define D_TOT 3072
#define NH    24
#define HD    128
#define BLK_R 2048
#define TIP   128
#define DIP   4096

typedef __attribute__((ext_vector_type(4))) float f4;
typedef __attribute__((ext_vector_type(8))) short bh8;
typedef unsigned short u16;
typedef unsigned int   u32;
typedef unsigned long long u64;

__device__ __forceinline__ u16 f2bf(float f) {
    u32 u = __float_as_uint(f);
    u32 r = (u + 0x7fffu + ((u >> 16) & 1u)) >> 16;
    return (u16)r;
}
__device__ __forceinline__ uint4 pack8u(float4 a, float4 b) {
    uint4 u;
    u.x = (u32)f2bf(a.x) | ((u32)f2bf(a.y) << 16);
    u.y = (u32)f2bf(a.z) | ((u32)f2bf(a.w) << 16);
    u.z = (u32)f2bf(b.x) | ((u32)f2bf(b.y) << 16);
    u.w = (u32)f2bf(b.z) | ((u32)f2bf(b.w) << 16);
    return u;
}
__device__ __forceinline__ bh8 pack8v(float4 a, float4 b) {
    bh8 v;
    v[0] = (short)f2bf(a.x); v[1] = (short)f2bf(a.y);
    v[2] = (short)f2bf(a.z); v[3] = (short)f2bf(a.w);
    v[4] = (short)f2bf(b.x); v[5] = (short)f2bf(b.y);
    v[6] = (short)f2bf(b.z); v[7] = (short)f2bf(b.w);
    return v;
}

// ---------------- GEMM: C[M][N] (+)= A[M][K] @ B[N][K]^T + bias ----------------
// A, B, bias f32 (converted to bf16 during LDS staging); C f32.
// 128x128 tile, BK=64, 4 waves (2x2), 4x4 mfma 16x16x32 each.
// mode 0: store (+bias). mode 1: C += (single writer). mode 2: atomicAdd (split-K, C pre-zeroed).
__global__ __launch_bounds__(256)
void gemm_f32(const float* __restrict__ A, const float* __restrict__ B,
              const float* __restrict__ bias, float* __restrict__ C,
              int M, int N, int K, int mode, int ksplit)
{
    __shared__ u16 As[128 * 64];
    __shared__ u16 Bs[128 * 64];
    const int tid  = threadIdx.x;
    const int wv   = tid >> 6;
    const int lane = tid & 63;
    const int quad = lane >> 4;
    const int l16  = lane & 15;
    const int wm   = (wv >> 1) << 6;
    const int wn   = (wv & 1) << 6;
    const int m0   = blockIdx.x << 7;
    const int n0   = blockIdx.y << 7;
    const int kch  = K / ksplit;
    const int kbeg = blockIdx.z * kch;
    const int kend = kbeg + kch;

    f4 acc[4][4] = {};

    for (int k0 = kbeg; k0 < kend; k0 += 64) {
#pragma unroll
        for (int p = 0; p < 4; ++p) {
            int idx = (p << 11) + (tid << 3);
            int r = idx >> 6, c = idx & 63;
            const float* ap = A + (size_t)(m0 + r) * K + k0 + c;
            *(uint4*)(&As[idx]) = pack8u(*(const float4*)ap, *(const float4*)(ap + 4));
            const float* bp = B + (size_t)(n0 + r) * K + k0 + c;
            *(uint4*)(&Bs[idx]) = pack8u(*(const float4*)bp, *(const float4*)(bp + 4));
        }
        __syncthreads();
#pragma unroll
        for (int kk = 0; kk < 2; ++kk) {
            bh8 a[4], b[4];
#pragma unroll
            for (int i = 0; i < 4; ++i)
                a[i] = *(const bh8*)(&As[(wm + (i << 4) + l16) * 64 + (kk << 5) + (quad << 3)]);
#pragma unroll
            for (int i = 0; i < 4; ++i)
                b[i] = *(const bh8*)(&Bs[(wn + (i << 4) + l16) * 64 + (kk << 5) + (quad << 3)]);
#pragma unroll
            for (int mt = 0; mt < 4; ++mt)
#pragma unroll
                for (int nt = 0; nt < 4; ++nt)
                    acc[mt][nt] = __builtin_amdgcn_mfma_f32_16x16x32_bf16(a[mt], b[nt], acc[mt][nt], 0, 0, 0);
        }
        __syncthreads();
    }
#pragma unroll
    for (int mt = 0; mt < 4; ++mt) {
#pragma unroll
        for (int nt = 0; nt < 4; ++nt) {
            int n = n0 + wn + (nt << 4) + l16;
            float bs = bias ? bias[n] : 0.0f;
#pragma unroll
            for (int r = 0; r < 4; ++r) {
                int m = m0 + wm + (mt << 4) + (quad << 2) + r;
                size_t o = (size_t)m * N + n;
                float v = acc[mt][nt][r] + bs;
                if (mode == 0)      C[o] = v;
                else if (mode == 1) C[o] += v;
                else                atomicAdd(&C[o], v);
            }
        }
    }
}

// ---------------- LoRA down: T1[s][r] = sum_d X[2048+s][d]*Dwn[r][d], f32 out ----------------
__global__ __launch_bounds__(256)
void lora_down_k(const float* __restrict__ X, const float* __restrict__ Dwn, float* __restrict__ T1)
{
    int wv = threadIdx.x >> 6, lane = threadIdx.x & 63;
    int quad = lane >> 4, l16 = lane & 15;
    int gw = blockIdx.x * 4 + wv;          // 0..127
    int mt = gw >> 3, nt = gw & 7;
    const float* ap = X + (size_t)(BLK_R + (mt << 4) + l16) * D_TOT + (quad << 3);
    const float* bp = Dwn + (size_t)((nt << 4) + l16) * D_TOT + (quad << 3);
    f4 acc = {};
    for (int c = 0; c < 96; ++c) {
        bh8 a = pack8v(*(const float4*)(ap + (c << 5)), *(const float4*)(ap + (c << 5) + 4));
        bh8 b = pack8v(*(const float4*)(bp + (c << 5)), *(const float4*)(bp + (c << 5) + 4));
        acc = __builtin_amdgcn_mfma_f32_16x16x32_bf16(a, b, acc, 0, 0, 0);
    }
#pragma unroll
    for (int r = 0; r < 4; ++r) {
        int s  = (mt << 4) + (quad << 2) + r;
        int rr = (nt << 4) + l16;
        T1[(size_t)s * 128 + rr] = acc[r];
    }
}

// ---------------- RMSNorm (+f32 weight) + optional RoPE; f32 [Slen][3072] -> bf16 [H][Slen][128]
// omul: post-norm/rope output scale (used to fold 1/sqrt(HD)*log2e into Q once).
template <int ROPE>
__global__ __launch_bounds__(256)
void norm_rope_k(const float* __restrict__ X, const float* __restrict__ w,
                 const float* __restrict__ ct, const float* __restrict__ st,
                 u16* __restrict__ Out, int Slen, float omul)
{
    int g = blockIdx.x * 4 + (threadIdx.x >> 6);
    int lane = threadIdx.x & 63;
    int s = g / NH, h = g % NH;
    const float* xp = X + (size_t)s * D_TOT + (h << 7) + (lane << 1);
    float2 xv = *(const float2*)xp;
    float ss = xv.x * xv.x + xv.y * xv.y;
#pragma unroll
    for (int off = 1; off <= 32; off <<= 1) ss += __shfl_xor(ss, off);
    float invr = rsqrtf(ss * (1.0f / 128.0f) + 1e-5f);
    float a = xv.x * invr, b = xv.y * invr;
    if (w) { a *= w[lane << 1]; b *= w[(lane << 1) + 1]; }
    float o0 = a, o1 = b;
    if (ROPE) {
        float c0 = ct[(size_t)s * HD + (lane << 1)], c1 = ct[(size_t)s * HD + (lane << 1) + 1];
        float n0 = st[(size_t)s * HD + (lane << 1)], n1 = st[(size_t)s * HD + (lane << 1) + 1];
        o0 = a * c0 - b * n0;
        o1 = b * c1 + a * n1;
    }
    o0 *= omul; o1 *= omul;
    size_t oo = ((size_t)h * Slen + s) * HD + (lane << 1);
    u32 pack = (u32)f2bf(o0) | ((u32)f2bf(o1) << 16);
    *(u32*)(&Out[oo]) = pack;
}

// ---------------- V transpose: f32 [Slen][3072] -> bf16 Vt[H][HD][Slen] ----------------
__global__ __launch_bounds__(256)
void transpose_v_k(const float* __restrict__ V, u16* __restrict__ Vt, int Slen)
{
    __shared__ u16 tile[64][130];
    int h = blockIdx.y;
    int s0 = blockIdx.x << 6;
    int tid = threadIdx.x;
#pragma unroll
    for (int p = 0; p < 32; ++p) {
        int flat = (p << 8) + tid;
        int si = flat >> 7, d = flat & 127;
        tile[si][d] = f2bf(V[(size_t)(s0 + si) * D_TOT + (h << 7) + d]);
    }
    __syncthreads();
#pragma unroll
    for (int p = 0; p < 32; ++p) {
        int flat = (p << 8) + tid;
        int d = flat >> 6, si = flat & 63;
        Vt[((size_t)(h << 7) + d) * Slen + s0 + si] = tile[si][d];
    }
}

// ---------------- MFMA flash attention (per-wave 16 q-rows, 32-key tiles) ----------------
// Qb [H][S_TOT][128] (pre-scaled by 1/sqrt(HD)*log2e), Kb [H][Lk][128], Vt [H][128][Lk];
// Out f32 [S_TOT][3072]. Q rows >= 2048 start at key tile cond_start. accum=1 RMWs Out.
// R2: flat loop (no lambda/pointer-indexed arrays — R1's scratch-spill lesson), early V
// register loads hidden under softmax, deferred l-sum reduction (alpha is row-uniform so
// per-lane partials stay exact), skip-rescale when tile max doesn't grow, setprio on MFMA.
__global__ __launch_bounds__(256)
void attn_k(const u16* __restrict__ Qb, const u16* __restrict__ Kb,
            const u16* __restrict__ Vt, float* __restrict__ Out,
            int Lk, int cond_start, int accum)
{
    __shared__ u16 Pl[4][16 * 40];   // per-wave P tile, rows padded to 40
    const int h = blockIdx.y;
    const int qt = blockIdx.x;
    const int wv = threadIdx.x >> 6;
    const int lane = threadIdx.x & 63;
    const int quad = lane >> 4, l16 = lane & 15;
    const int sb = (qt << 6) + (wv << 4);

    bh8 qf[4];
    const u16* qp = Qb + ((size_t)h * S_TOT + sb + l16) * HD + (quad << 3);
#pragma unroll
    for (int c = 0; c < 4; ++c) qf[c] = *(const bh8*)(qp + (c << 5));

    f4 o[8] = {};
    float mrow[4]  = {-1e30f, -1e30f, -1e30f, -1e30f};
    float lpart[4] = {0.f, 0.f, 0.f, 0.f};   // per-lane partial row sum (reduced after loop)
    u16* pl = &Pl[wv][0];

    const int kt0 = (sb >= BLK_R) ? cond_start : 0;
    const int ktN = Lk >> 5;
    const u16* kbase = Kb + ((size_t)h * Lk + l16) * HD + (quad << 3);
    const u16* vbase = Vt + ((size_t)(h << 7) + l16) * Lk + (quad << 3);

    for (int kt = kt0; kt < ktN; ++kt) {
        const u16* kp = kbase + ((size_t)kt << 5) * HD;
        const u16* vp = vbase + ((size_t)kt << 5);
        // K tile (32 rows) into registers
        bh8 kk0[4], kk1[4];
#pragma unroll
        for (int c = 0; c < 4; ++c) {
            kk0[c] = *(const bh8*)(kp + (c << 5));
            kk1[c] = *(const bh8*)(kp + 2048 + (c << 5));   // +16 key rows * 128
        }
        // V tile loads issued NOW: latency hides under QK mfma + softmax
        bh8 vv[8];
#pragma unroll
        for (int dt = 0; dt < 8; ++dt)
            vv[dt] = *(const bh8*)(vp + ((size_t)dt << 4) * Lk);

        f4 s0 = {}, s1 = {};
        __builtin_amdgcn_s_setprio(1);
#pragma unroll
        for (int c = 0; c < 4; ++c) {
            s0 = __builtin_amdgcn_mfma_f32_16x16x32_bf16(qf[c], kk0[c], s0, 0, 0, 0);
            s1 = __builtin_amdgcn_mfma_f32_16x16x32_bf16(qf[c], kk1[c], s1, 0, 0, 0);
        }
        __builtin_amdgcn_s_setprio(0);

        float mx[4];
#pragma unroll
        for (int r = 0; r < 4; ++r) mx[r] = fmaxf(s0[r], s1[r]);
#pragma unroll
        for (int off = 1; off <= 8; off <<= 1)
#pragma unroll
            for (int r = 0; r < 4; ++r) mx[r] = fmaxf(mx[r], __shfl_xor(mx[r], off));

        // rescale only when the running max actually grew (wave-uniform branch)
        int grow = 0;
#pragma unroll
        for (int r = 0; r < 4; ++r) grow |= (mx[r] > mrow[r]) ? 1 : 0;
        if (__any(grow)) {
#pragma unroll
            for (int r = 0; r < 4; ++r) {
                float mn = fmaxf(mrow[r], mx[r]);
                float al = exp2f(mrow[r] - mn);
                mrow[r] = mn;
                lpart[r] *= al;
#pragma unroll
                for (int dt = 0; dt < 8; ++dt) o[dt][r] *= al;
            }
        }
        float p0[4], p1[4];
#pragma unroll
        for (int r = 0; r < 4; ++r) {
            p0[r] = exp2f(s0[r] - mrow[r]);
            p1[r] = exp2f(s1[r] - mrow[r]);
            lpart[r] += p0[r] + p1[r];
        }
        // P (C-layout) -> LDS -> A-layout (wave-internal, lgkmcnt-ordered, no barrier)
#pragma unroll
        for (int r = 0; r < 4; ++r) {
            pl[((quad << 2) + r) * 40 + l16]      = f2bf(p0[r]);
            pl[((quad << 2) + r) * 40 + 16 + l16] = f2bf(p1[r]);
        }
        bh8 pa = *(const bh8*)(pl + l16 * 40 + (quad << 3));
        __builtin_amdgcn_s_setprio(1);
#pragma unroll
        for (int dt = 0; dt < 8; ++dt)
            o[dt] = __builtin_amdgcn_mfma_f32_16x16x32_bf16(pa, vv[dt], o[dt], 0, 0, 0);
        __builtin_amdgcn_s_setprio(0);
    }

    // final cross-lane row-sum reduction (once, instead of per tile)
#pragma unroll
    for (int off = 1; off <= 8; off <<= 1)
#pragma unroll
        for (int r = 0; r < 4; ++r) lpart[r] += __shfl_xor(lpart[r], off);
    float inv[4];
#pragma unroll
    for (int r = 0; r < 4; ++r) inv[r] = 1.0f / lpart[r];
#pragma unroll
    for (int dt = 0; dt < 8; ++dt) {
#pragma unroll
        for (int r = 0; r < 4; ++r) {
            int row = sb + (quad << 2) + r;
            int col = (h << 7) + (dt << 4) + l16;
            size_t idx = (size_t)row * D_TOT + col;
            float v = o[dt][r] * inv[r];
            if (accum) v += Out[idx];
            Out[idx] = v;
        }
    }
}

// ---------------- workspace layout (byte offsets), total ~132.5 MB (ws >= 215 MB verified R1) ----
static const u64 B_QF   = 0;           // fp32 [2304][3072]
static const u64 B_KF   = 28311552;
static const u64 B_VF   = 56623104;
static const u64 B_KIPF = 84934656;    // fp32 [128][3072]
static const u64 B_VIPF = 86507520;
static const u64 B_T1   = 88080384;    // fp32 [3][256][128]
static const u64 B_QB   = 88473600;    // bf16 [24][2304][128]
static const u64 B_KB   = 102629376;
static const u64 B_VT   = 116785152;   // bf16 [24][128][2304]
static const u64 B_KIPB = 130940928;   // bf16 [24][128][128]
static const u64 B_VIPT = 131727360;   // bf16 [24][128][128]

extern "C" void kernel_launch(void* const* d_in, const int* in_sizes, int n_in,
                              void* d_out, int out_size, void* d_ws, size_t ws_size,
                              hipStream_t stream) {
    (void)in_sizes; (void)n_in; (void)out_size; (void)ws_size;
    const float* x    = (const float*)d_in[0];
    const float* img  = (const float*)d_in[1];
    const float* rc   = (const float*)d_in[2];
    const float* rsn  = (const float*)d_in[3];
    const float* Wq   = (const float*)d_in[4];
    const float* bq   = (const float*)d_in[5];
    const float* Wk   = (const float*)d_in[6];
    const float* bk   = (const float*)d_in[7];
    const float* Wv   = (const float*)d_in[8];
    const float* bv   = (const float*)d_in[9];
    const float* qdn  = (const float*)d_in[10];
    const float* qup  = (const float*)d_in[11];
    const float* kdn  = (const float*)d_in[12];
    const float* kup  = (const float*)d_in[13];
    const float* vdn  = (const float*)d_in[14];
    const float* vup  = (const float*)d_in[15];
    const float* nqw  = (const float*)d_in[16];
    const float* nkw  = (const float*)d_in[17];
    const float* Wkip = (const float*)d_in[18];
    const float* Wvip = (const float*)d_in[19];

    float* qf   = (float*)((char*)d_ws + B_QF);
    float* kf   = (float*)((char*)d_ws + B_KF);
    float* vf   = (float*)((char*)d_ws + B_VF);
    float* kipf = (float*)((char*)d_ws + B_KIPF);
    float* vipf = (float*)((char*)d_ws + B_VIPF);
    float* t1   = (float*)((char*)d_ws + B_T1);
    u16*   Qb   = (u16*)((char*)d_ws + B_QB);
    u16*   Kb   = (u16*)((char*)d_ws + B_KB);
    u16*   Vt   = (u16*)((char*)d_ws + B_VT);
    u16*   Kipb = (u16*)((char*)d_ws + B_KIPB);
    u16*   Vipt = (u16*)((char*)d_ws + B_VIPT);
    float* outf = (float*)d_out;

    const float QSCALE = 0.08838834764831845f * 1.4426950408889634f;  // 1/sqrt(128) * log2(e)

    // zero the split-K atomic accumulation targets
    hipMemsetAsync((char*)d_ws + B_KIPF, 0, 2 * 1572864, stream);

    // 1) QKV projections: [2304][3072] = x @ W^T + bias (fp32 out)
    gemm_f32<<<dim3(18, 24, 1), dim3(256), 0, stream>>>(x, Wq, bq, qf, S_TOT, D_TOT, D_TOT, 0, 1);
    gemm_f32<<<dim3(18, 24, 1), dim3(256), 0, stream>>>(x, Wk, bk, kf, S_TOT, D_TOT, D_TOT, 0, 1);
    gemm_f32<<<dim3(18, 24, 1), dim3(256), 0, stream>>>(x, Wv, bv, vf, S_TOT, D_TOT, D_TOT, 0, 1);

    // 2) LoRA: down (t1 = x_cond @ down^T), then up (+= into rows 2048..2303)
    lora_down_k<<<dim3(32), dim3(256), 0, stream>>>(x, qdn, t1);
    lora_down_k<<<dim3(32), dim3(256), 0, stream>>>(x, kdn, t1 + 32768);
    lora_down_k<<<dim3(32), dim3(256), 0, stream>>>(x, vdn, t1 + 65536);
    gemm_f32<<<dim3(2, 24, 1), dim3(256), 0, stream>>>(t1,         qup, nullptr, qf + (size_t)BLK_R * D_TOT, 256, D_TOT, 128, 1, 1);
    gemm_f32<<<dim3(2, 24, 1), dim3(256), 0, stream>>>(t1 + 32768, kup, nullptr, kf + (size_t)BLK_R * D_TOT, 256, D_TOT, 128, 1, 1);
    gemm_f32<<<dim3(2, 24, 1), dim3(256), 0, stream>>>(t1 + 65536, vup, nullptr, vf + (size_t)BLK_R * D_TOT, 256, D_TOT, 128, 1, 1);

    // 3) IP projections: [128][3072] = img @ W_ip^T (split-K=8, atomic into zeroed fp32)
    gemm_f32<<<dim3(1, 24, 8), dim3(256), 0, stream>>>(img, Wkip, nullptr, kipf, TIP, D_TOT, DIP, 2, 8);
    gemm_f32<<<dim3(1, 24, 8), dim3(256), 0, stream>>>(img, Wvip, nullptr, vipf, TIP, D_TOT, DIP, 2, 8);

    // 4) norm (+rope) -> head-major bf16 (Q pre-scaled); V transposes
    norm_rope_k<1><<<dim3(13824), dim3(256), 0, stream>>>(qf, nqw, rc, rsn, Qb, S_TOT, QSCALE);
    norm_rope_k<1><<<dim3(13824), dim3(256), 0, stream>>>(kf, nkw, rc, rsn, Kb, S_TOT, 1.0f);
    norm_rope_k<0><<<dim3(768),   dim3(256), 0, stream>>>(kipf, nullptr, nullptr, nullptr, Kipb, TIP, 1.0f);
    transpose_v_k<<<dim3(36, 24), dim3(256), 0, stream>>>(vf, Vt, S_TOT);
    transpose_v_k<<<dim3(2, 24),  dim3(256), 0, stream>>>(vipf, Vipt, TIP);

    // 5) attention: main writes f32 out; IP attention accumulates (RMW)
    attn_k<<<dim3(36, 24), dim3(256), 0, stream>>>(Qb, Kb,   Vt,   outf, S_TOT, 64, 0);
    attn_k<<<dim3(36, 24), dim3(256), 0, stream>>>(Qb, Kipb, Vipt, outf, TIP,   0,  1);
}

// Round 3
// 1239.658 us; speedup vs baseline: 1.5480x; 1.4133x over previous
//
#include <hip/hip_runtime.h>

#define S_TOT 2304
#define D_TOT 3072
#define NH    24
#define HD    128
#define BLK_R 2048
#define TIP   128
#define DIP   4096
#define KS    3      // attention split-K chunks (per = 24 key-tiles)

typedef __attribute__((ext_vector_type(4))) float f4;
typedef __attribute__((ext_vector_type(8))) short bh8;
typedef unsigned short u16;
typedef unsigned int   u32;
typedef unsigned long long u64;

__device__ __forceinline__ u16 f2bf(float f) {
    u32 u = __float_as_uint(f);
    u32 r = (u + 0x7fffu + ((u >> 16) & 1u)) >> 16;
    return (u16)r;
}
__device__ __forceinline__ uint4 pack8u(float4 a, float4 b) {
    uint4 u;
    u.x = (u32)f2bf(a.x) | ((u32)f2bf(a.y) << 16);
    u.y = (u32)f2bf(a.z) | ((u32)f2bf(a.w) << 16);
    u.z = (u32)f2bf(b.x) | ((u32)f2bf(b.y) << 16);
    u.w = (u32)f2bf(b.z) | ((u32)f2bf(b.w) << 16);
    return u;
}
__device__ __forceinline__ bh8 pack8v(float4 a, float4 b) {
    bh8 v;
    v[0] = (short)f2bf(a.x); v[1] = (short)f2bf(a.y);
    v[2] = (short)f2bf(a.z); v[3] = (short)f2bf(a.w);
    v[4] = (short)f2bf(b.x); v[5] = (short)f2bf(b.y);
    v[6] = (short)f2bf(b.z); v[7] = (short)f2bf(b.w);
    return v;
}

// ---------------- GEMM body: C[M][N] (+)= A[M][K] @ B[N][K]^T + bias ----------------
// 128x128 tile, BK=64, 4 waves (2x2), 4x4 mfma 16x16x32 each. Uses blockIdx.x/y for tile.
// mode 0: store (+bias). mode 1: C += (single writer). mode 2: atomicAdd (C pre-zeroed).
__device__ __forceinline__ void gemm_body(const float* __restrict__ A, const float* __restrict__ B,
                                          const float* __restrict__ bias, float* __restrict__ C,
                                          int M, int N, int K, int mode, int kbeg, int kend,
                                          u16* As, u16* Bs)
{
    const int tid  = threadIdx.x;
    const int wv   = tid >> 6;
    const int lane = tid & 63;
    const int quad = lane >> 4;
    const int l16  = lane & 15;
    const int wm   = (wv >> 1) << 6;
    const int wn   = (wv & 1) << 6;
    const int m0   = blockIdx.x << 7;
    const int n0   = blockIdx.y << 7;

    f4 acc[4][4] = {};

    for (int k0 = kbeg; k0 < kend; k0 += 64) {
#pragma unroll
        for (int p = 0; p < 4; ++p) {
            int idx = (p << 11) + (tid << 3);
            int r = idx >> 6, c = idx & 63;
            const float* ap = A + (size_t)(m0 + r) * K + k0 + c;
            *(uint4*)(&As[idx]) = pack8u(*(const float4*)ap, *(const float4*)(ap + 4));
            const float* bp = B + (size_t)(n0 + r) * K + k0 + c;
            *(uint4*)(&Bs[idx]) = pack8u(*(const float4*)bp, *(const float4*)(bp + 4));
        }
        __syncthreads();
#pragma unroll
        for (int kk = 0; kk < 2; ++kk) {
            bh8 a[4], b[4];
#pragma unroll
            for (int i = 0; i < 4; ++i)
                a[i] = *(const bh8*)(&As[(wm + (i << 4) + l16) * 64 + (kk << 5) + (quad << 3)]);
#pragma unroll
            for (int i = 0; i < 4; ++i)
                b[i] = *(const bh8*)(&Bs[(wn + (i << 4) + l16) * 64 + (kk << 5) + (quad << 3)]);
#pragma unroll
            for (int mt = 0; mt < 4; ++mt)
#pragma unroll
                for (int nt = 0; nt < 4; ++nt)
                    acc[mt][nt] = __builtin_amdgcn_mfma_f32_16x16x32_bf16(a[mt], b[nt], acc[mt][nt], 0, 0, 0);
        }
        __syncthreads();
    }
#pragma unroll
    for (int mt = 0; mt < 4; ++mt) {
#pragma unroll
        for (int nt = 0; nt < 4; ++nt) {
            int n = n0 + wn + (nt << 4) + l16;
            float bs = bias ? bias[n] : 0.0f;
#pragma unroll
            for (int r = 0; r < 4; ++r) {
                int m = m0 + wm + (mt << 4) + (quad << 2) + r;
                size_t o = (size_t)m * N + n;
                float v = acc[mt][nt][r] + bs;
                if (mode == 0)      C[o] = v;
                else if (mode == 1) C[o] += v;
                else                atomicAdd(&C[o], v);
            }
        }
    }
}

// QKV fused: blockIdx.z selects (W, bias, C). grid (18,24,3) = 1296 blocks (5 blk/CU at 32KB LDS).
__global__ __launch_bounds__(256)
void gemm_qkv_k(const float* __restrict__ x,
                const float* __restrict__ Wq, const float* __restrict__ bq, float* __restrict__ qf,
                const float* __restrict__ Wk, const float* __restrict__ bk, float* __restrict__ kf,
                const float* __restrict__ Wv, const float* __restrict__ bv, float* __restrict__ vf)
{
    __shared__ u16 As[128 * 64];
    __shared__ u16 Bs[128 * 64];
    int z = blockIdx.z;
    const float* B  = z == 0 ? Wq : (z == 1 ? Wk : Wv);
    const float* bi = z == 0 ? bq : (z == 1 ? bk : bv);
    float*       C  = z == 0 ? qf : (z == 1 ? kf : vf);
    gemm_body(x, B, bi, C, S_TOT, D_TOT, D_TOT, 0, 0, D_TOT, As, Bs);
}

// LoRA up fused: grid (2,24,3); C += t1_z @ up_z^T into rows 2048..2303.
__global__ __launch_bounds__(256)
void gemm_loraup_k(const float* __restrict__ t1,
                   const float* __restrict__ qup, const float* __restrict__ kup, const float* __restrict__ vup,
                   float* __restrict__ qf, float* __restrict__ kf, float* __restrict__ vf)
{
    __shared__ u16 As[128 * 64];
    __shared__ u16 Bs[128 * 64];
    int z = blockIdx.z;
    const float* A = t1 + (size_t)z * 32768;
    const float* B = z == 0 ? qup : (z == 1 ? kup : vup);
    float*       C = (z == 0 ? qf : (z == 1 ? kf : vf)) + (size_t)BLK_R * D_TOT;
    gemm_body(A, B, nullptr, C, 256, D_TOT, 128, 1, 0, 128, As, Bs);
}

// IP projections fused: grid (1,24,16); z>>3 selects K/V, z&7 selects K-chunk (split-K=8, atomics).
__global__ __launch_bounds__(256)
void gemm_ip_k(const float* __restrict__ img,
               const float* __restrict__ Wkip, const float* __restrict__ Wvip,
               float* __restrict__ kipf, float* __restrict__ vipf)
{
    __shared__ u16 As[128 * 64];
    __shared__ u16 Bs[128 * 64];
    int z = blockIdx.z;
    int sel = z >> 3, cz = z & 7;
    const float* B = sel ? Wvip : Wkip;
    float*       C = sel ? vipf : kipf;
    gemm_body(img, B, nullptr, C, TIP, D_TOT, DIP, 2, cz * 512, cz * 512 + 512, As, Bs);
}

// ---------------- LoRA down fused: grid (32,3); T1_y[s][r] = sum_d X[2048+s][d]*Dwn_y[r][d] ----
__global__ __launch_bounds__(256)
void lora_down_k(const float* __restrict__ X,
                 const float* __restrict__ qdn, const float* __restrict__ kdn, const float* __restrict__ vdn,
                 float* __restrict__ t1)
{
    int y = blockIdx.y;
    const float* Dwn = y == 0 ? qdn : (y == 1 ? kdn : vdn);
    float* T1 = t1 + (size_t)y * 32768;
    int wv = threadIdx.x >> 6, lane = threadIdx.x & 63;
    int quad = lane >> 4, l16 = lane & 15;
    int gw = blockIdx.x * 4 + wv;          // 0..127
    int mt = gw >> 3, nt = gw & 7;
    const float* ap = X + (size_t)(BLK_R + (mt << 4) + l16) * D_TOT + (quad << 3);
    const float* bp = Dwn + (size_t)((nt << 4) + l16) * D_TOT + (quad << 3);
    f4 acc = {};
    for (int c = 0; c < 96; ++c) {
        bh8 a = pack8v(*(const float4*)(ap + (c << 5)), *(const float4*)(ap + (c << 5) + 4));
        bh8 b = pack8v(*(const float4*)(bp + (c << 5)), *(const float4*)(bp + (c << 5) + 4));
        acc = __builtin_amdgcn_mfma_f32_16x16x32_bf16(a, b, acc, 0, 0, 0);
    }
#pragma unroll
    for (int r = 0; r < 4; ++r) {
        int s  = (mt << 4) + (quad << 2) + r;
        int rr = (nt << 4) + l16;
        T1[(size_t)s * 128 + rr] = acc[r];
    }
}

// ---------------- RMSNorm (+f32 weight) + optional RoPE body ----------------
template <int ROPE>
__device__ __forceinline__ void norm_rope_body(const float* __restrict__ X, const float* __restrict__ w,
                                               const float* __restrict__ ct, const float* __restrict__ st,
                                               u16* __restrict__ Out, int Slen, float omul, int g, int lane)
{
    int s = g / NH, h = g % NH;
    const float* xp = X + (size_t)s * D_TOT + (h << 7) + (lane << 1);
    float2 xv = *(const float2*)xp;
    float ss = xv.x * xv.x + xv.y * xv.y;
#pragma unroll
    for (int off = 1; off <= 32; off <<= 1) ss += __shfl_xor(ss, off);
    float invr = rsqrtf(ss * (1.0f / 128.0f) + 1e-5f);
    float a = xv.x * invr, b = xv.y * invr;
    if (w) { a *= w[lane << 1]; b *= w[(lane << 1) + 1]; }
    float o0 = a, o1 = b;
    if (ROPE) {
        float c0 = ct[(size_t)s * HD + (lane << 1)], c1 = ct[(size_t)s * HD + (lane << 1) + 1];
        float n0 = st[(size_t)s * HD + (lane << 1)], n1 = st[(size_t)s * HD + (lane << 1) + 1];
        o0 = a * c0 - b * n0;
        o1 = b * c1 + a * n1;
    }
    o0 *= omul; o1 *= omul;
    size_t oo = ((size_t)h * Slen + s) * HD + (lane << 1);
    u32 pack = (u32)f2bf(o0) | ((u32)f2bf(o1) << 16);
    *(u32*)(&Out[oo]) = pack;
}

// Q and K fused: grid (13824, 2). y=0: Q (pre-scaled), y=1: K.
__global__ __launch_bounds__(256)
void norm_qk_k(const float* __restrict__ qf, const float* __restrict__ kf,
               const float* __restrict__ nqw, const float* __restrict__ nkw,
               const float* __restrict__ ct, const float* __restrict__ st,
               u16* __restrict__ Qb, u16* __restrict__ Kb, float qscale)
{
    int g = blockIdx.x * 4 + (threadIdx.x >> 6);
    int lane = threadIdx.x & 63;
    if (blockIdx.y == 0)
        norm_rope_body<1>(qf, nqw, ct, st, Qb, S_TOT, qscale, g, lane);
    else
        norm_rope_body<1>(kf, nkw, ct, st, Kb, S_TOT, 1.0f, g, lane);
}

__global__ __launch_bounds__(256)
void norm_ip_k(const float* __restrict__ X, u16* __restrict__ Out)
{
    int g = blockIdx.x * 4 + (threadIdx.x >> 6);
    int lane = threadIdx.x & 63;
    norm_rope_body<0>(X, nullptr, nullptr, nullptr, Out, TIP, 1.0f, g, lane);
}

// ---------------- V transpose: f32 [Slen][3072] -> bf16 Vt[H][HD][Slen] ----------------
__global__ __launch_bounds__(256)
void transpose_v_k(const float* __restrict__ V, u16* __restrict__ Vt, int Slen)
{
    __shared__ u16 tile[64][130];
    int h = blockIdx.y;
    int s0 = blockIdx.x << 6;
    int tid = threadIdx.x;
#pragma unroll
    for (int p = 0; p < 32; ++p) {
        int flat = (p << 8) + tid;
        int si = flat >> 7, d = flat & 127;
        tile[si][d] = f2bf(V[(size_t)(s0 + si) * D_TOT + (h << 7) + d]);
    }
    __syncthreads();
#pragma unroll
    for (int p = 0; p < 32; ++p) {
        int flat = (p << 8) + tid;
        int d = flat >> 6, si = flat & 63;
        Vt[((size_t)(h << 7) + d) * Slen + s0 + si] = tile[si][d];
    }
}

// ---------------- MFMA flash attention, split-K over key tiles ----------------
// Qb [H][S_TOT][128] (pre-scaled by 1/sqrt(HD)*log2e), Kb [H][Lk][128], Vt [H][128][Lk].
// chunk c=blockIdx.z covers key-tiles [c*per, (c+1)*per) ∩ [kt0, Lk/32).
// mode 0: normalized write to Out[row*D_TOT+col] (IP attention, single chunk).
// mode 1: store unnormalized partial O (f32) to Opart[c][h][row][128] and (m,l) to Ml[c][h][row].
__global__ __launch_bounds__(256)
void attn_k(const u16* __restrict__ Qb, const u16* __restrict__ Kb,
            const u16* __restrict__ Vt, float* __restrict__ Out,
            float* __restrict__ Opart, float2* __restrict__ Ml,
            int Lk, int cond_start, int per, int mode)
{
    __shared__ u16 Pl[4][16 * 40];   // per-wave P tile, rows padded to 40
    const int h = blockIdx.y;
    const int qt = blockIdx.x;
    const int ch = blockIdx.z;
    const int wv = threadIdx.x >> 6;
    const int lane = threadIdx.x & 63;
    const int quad = lane >> 4, l16 = lane & 15;
    const int sb = (qt << 6) + (wv << 4);

    bh8 qf[4];
    const u16* qp = Qb + ((size_t)h * S_TOT + sb + l16) * HD + (quad << 3);
#pragma unroll
    for (int c = 0; c < 4; ++c) qf[c] = *(const bh8*)(qp + (c << 5));

    f4 o[8] = {};
    float mrow[4]  = {-1e30f, -1e30f, -1e30f, -1e30f};
    float lpart[4] = {0.f, 0.f, 0.f, 0.f};   // per-lane partial row sum (reduced after loop)
    u16* pl = &Pl[wv][0];

    const int kt0 = (sb >= BLK_R) ? cond_start : 0;
    const int ktN = Lk >> 5;
    int kt_lo = ch * per;     if (kt0 > kt_lo) kt_lo = kt0;
    int kt_hi = ch * per + per; if (ktN < kt_hi) kt_hi = ktN;

    const u16* kbase = Kb + ((size_t)h * Lk + l16) * HD + (quad << 3);
    const u16* vbase = Vt + ((size_t)(h << 7) + l16) * Lk + (quad << 3);

    for (int kt = kt_lo; kt < kt_hi; ++kt) {
        const u16* kp = kbase + ((size_t)kt << 5) * HD;
        const u16* vp = vbase + ((size_t)kt << 5);
        bh8 kk0[4], kk1[4];
#pragma unroll
        for (int c = 0; c < 4; ++c) {
            kk0[c] = *(const bh8*)(kp + (c << 5));
            kk1[c] = *(const bh8*)(kp + 2048 + (c << 5));   // +16 key rows * 128
        }
        bh8 vv[8];
#pragma unroll
        for (int dt = 0; dt < 8; ++dt)
            vv[dt] = *(const bh8*)(vp + ((size_t)dt << 4) * Lk);

        f4 s0 = {}, s1 = {};
        __builtin_amdgcn_s_setprio(1);
#pragma unroll
        for (int c = 0; c < 4; ++c) {
            s0 = __builtin_amdgcn_mfma_f32_16x16x32_bf16(qf[c], kk0[c], s0, 0, 0, 0);
            s1 = __builtin_amdgcn_mfma_f32_16x16x32_bf16(qf[c], kk1[c], s1, 0, 0, 0);
        }
        __builtin_amdgcn_s_setprio(0);

        float mx[4];
#pragma unroll
        for (int r = 0; r < 4; ++r) mx[r] = fmaxf(s0[r], s1[r]);
#pragma unroll
        for (int off = 1; off <= 8; off <<= 1)
#pragma unroll
            for (int r = 0; r < 4; ++r) mx[r] = fmaxf(mx[r], __shfl_xor(mx[r], off));

        int grow = 0;
#pragma unroll
        for (int r = 0; r < 4; ++r) grow |= (mx[r] > mrow[r]) ? 1 : 0;
        if (__any(grow)) {
#pragma unroll
            for (int r = 0; r < 4; ++r) {
                float mn = fmaxf(mrow[r], mx[r]);
                float al = exp2f(mrow[r] - mn);
                mrow[r] = mn;
                lpart[r] *= al;
#pragma unroll
                for (int dt = 0; dt < 8; ++dt) o[dt][r] *= al;
            }
        }
        float p0[4], p1[4];
#pragma unroll
        for (int r = 0; r < 4; ++r) {
            p0[r] = exp2f(s0[r] - mrow[r]);
            p1[r] = exp2f(s1[r] - mrow[r]);
            lpart[r] += p0[r] + p1[r];
        }
#pragma unroll
        for (int r = 0; r < 4; ++r) {
            pl[((quad << 2) + r) * 40 + l16]      = f2bf(p0[r]);
            pl[((quad << 2) + r) * 40 + 16 + l16] = f2bf(p1[r]);
        }
        bh8 pa = *(const bh8*)(pl + l16 * 40 + (quad << 3));
        __builtin_amdgcn_s_setprio(1);
#pragma unroll
        for (int dt = 0; dt < 8; ++dt)
            o[dt] = __builtin_amdgcn_mfma_f32_16x16x32_bf16(pa, vv[dt], o[dt], 0, 0, 0);
        __builtin_amdgcn_s_setprio(0);
    }

    // final cross-lane row-sum reduction (once)
#pragma unroll
    for (int off = 1; off <= 8; off <<= 1)
#pragma unroll
        for (int r = 0; r < 4; ++r) lpart[r] += __shfl_xor(lpart[r], off);

    if (mode == 0) {
        float inv[4];
#pragma unroll
        for (int r = 0; r < 4; ++r) inv[r] = 1.0f / lpart[r];
#pragma unroll
        for (int dt = 0; dt < 8; ++dt) {
#pragma unroll
            for (int r = 0; r < 4; ++r) {
                int row = sb + (quad << 2) + r;
                int col = (h << 7) + (dt << 4) + l16;
                Out[(size_t)row * D_TOT + col] = o[dt][r] * inv[r];
            }
        }
    } else {
        const size_t cb = ((size_t)ch * NH + h) * S_TOT;
#pragma unroll
        for (int dt = 0; dt < 8; ++dt) {
#pragma unroll
            for (int r = 0; r < 4; ++r) {
                int row = sb + (quad << 2) + r;
                Opart[(cb + row) * 128 + (dt << 4) + l16] = o[dt][r];
            }
        }
        if (l16 == 0) {
#pragma unroll
            for (int r = 0; r < 4; ++r) {
                int row = sb + (quad << 2) + r;
                Ml[cb + row] = (float2){mrow[r], lpart[r]};
            }
        }
    }
}

// ---------------- merge: Out = (Σ_c w_c O_c)/(Σ_c w_c l_c) + ipo; w_c = exp2(m_c - M) ----------
__global__ __launch_bounds__(256)
void merge_k(const float* __restrict__ Opart, const float2* __restrict__ Ml,
             const float* __restrict__ ipo, float* __restrict__ Out)
{
    int g = blockIdx.x * 4 + (threadIdx.x >> 6);   // (h,s) row id, 0..55295
    int lane = threadIdx.x & 63;
    int h = g / S_TOT;
    int s = g - h * S_TOT;
    float m[KS], l[KS];
#pragma unroll
    for (int c = 0; c < KS; ++c) {
        float2 ml = Ml[((size_t)c * NH + h) * S_TOT + s];
        m[c] = ml.x; l[c] = ml.y;
    }
    float M = m[0];
#pragma unroll
    for (int c = 1; c < KS; ++c) M = fmaxf(M, m[c]);
    float w[KS], lt = 0.f;
#pragma unroll
    for (int c = 0; c < KS; ++c) { w[c] = exp2f(m[c] - M); lt += w[c] * l[c]; }
    float inv = 1.0f / lt;
    float ax = 0.f, ay = 0.f;
#pragma unroll
    for (int c = 0; c < KS; ++c) {
        const float2 ov = *(const float2*)&Opart[(((size_t)c * NH + h) * S_TOT + s) * 128 + (lane << 1)];
        ax += w[c] * ov.x; ay += w[c] * ov.y;
    }
    size_t oidx = (size_t)s * D_TOT + (h << 7) + (lane << 1);
    float2 ip = *(const float2*)&ipo[oidx];
    float2 res = {ax * inv + ip.x, ay * inv + ip.y};
    *(float2*)&Out[oidx] = res;
}

// ---------------- workspace layout (byte offsets); ws >= 215 MB verified ----------------
// Opart [KS][24][2304][128] f32 (84.9 MB) reuses the qf/kf/vf region: those are fully
// consumed (norm/transpose) before any attn_k runs on the same stream.
static const u64 B_OP   = 0;           // f32 [3][24][2304][128] = 84,934,656 B
static const u64 B_QF   = 0;           // fp32 [2304][3072] (dead before attn)
static const u64 B_KF   = 28311552;
static const u64 B_VF   = 56623104;
static const u64 B_KIPF = 84934656;    // fp32 [128][3072]
static const u64 B_VIPF = 86507520;
static const u64 B_T1   = 88080384;    // fp32 [3][256][128]
static const u64 B_QB   = 88473600;    // bf16 [24][2304][128]
static const u64 B_KB   = 102629376;
static const u64 B_VT   = 116785152;   // bf16 [24][128][2304]
static const u64 B_KIPB = 130940928;   // bf16 [24][128][128]
static const u64 B_VIPT = 131727360;   // bf16 [24][128][128]
static const u64 B_ML   = 132513792;   // float2 [3][24][2304] = 1,327,104 B
static const u64 B_IPO  = 134217728;   // f32 [2304][3072] = 28,311,552 B (ends ~162.5 MB)

extern "C" void kernel_launch(void* const* d_in, const int* in_sizes, int n_in,
                              void* d_out, int out_size, void* d_ws, size_t ws_size,
                              hipStream_t stream) {
    (void)in_sizes; (void)n_in; (void)out_size; (void)ws_size;
    const float* x    = (const float*)d_in[0];
    const float* img  = (const float*)d_in[1];
    const float* rc   = (const float*)d_in[2];
    const float* rsn  = (const float*)d_in[3];
    const float* Wq   = (const float*)d_in[4];
    const float* bq   = (const float*)d_in[5];
    const float* Wk   = (const float*)d_in[6];
    const float* bk   = (const float*)d_in[7];
    const float* Wv   = (const float*)d_in[8];
    const float* bv   = (const float*)d_in[9];
    const float* qdn  = (const float*)d_in[10];
    const float* qup  = (const float*)d_in[11];
    const float* kdn  = (const float*)d_in[12];
    const float* kup  = (const float*)d_in[13];
    const float* vdn  = (const float*)d_in[14];
    const float* vup  = (const float*)d_in[15];
    const float* nqw  = (const float*)d_in[16];
    const float* nkw  = (const float*)d_in[17];
    const float* Wkip = (const float*)d_in[18];
    const float* Wvip = (const float*)d_in[19];

    float*  qf   = (float*)((char*)d_ws + B_QF);
    float*  kf   = (float*)((char*)d_ws + B_KF);
    float*  vf   = (float*)((char*)d_ws + B_VF);
    float*  kipf = (float*)((char*)d_ws + B_KIPF);
    float*  vipf = (float*)((char*)d_ws + B_VIPF);
    float*  t1   = (float*)((char*)d_ws + B_T1);
    u16*    Qb   = (u16*)((char*)d_ws + B_QB);
    u16*    Kb   = (u16*)((char*)d_ws + B_KB);
    u16*    Vt   = (u16*)((char*)d_ws + B_VT);
    u16*    Kipb = (u16*)((char*)d_ws + B_KIPB);
    u16*    Vipt = (u16*)((char*)d_ws + B_VIPT);
    float*  opart= (float*)((char*)d_ws + B_OP);
    float2* ml   = (float2*)((char*)d_ws + B_ML);
    float*  ipo  = (float*)((char*)d_ws + B_IPO);
    float*  outf = (float*)d_out;

    const float QSCALE = 0.08838834764831845f * 1.4426950408889634f;  // 1/sqrt(128) * log2(e)

    // zero the split-K atomic accumulation targets (IP projections)
    hipMemsetAsync((char*)d_ws + B_KIPF, 0, 2 * 1572864, stream);

    // 1) QKV projections fused: [2304][3072] = x @ W^T + bias (fp32 out)
    gemm_qkv_k<<<dim3(18, 24, 3), dim3(256), 0, stream>>>(x, Wq, bq, qf, Wk, bk, kf, Wv, bv, vf);

    // 2) LoRA: down fused (3-way), then up fused (+= into rows 2048..2303)
    lora_down_k<<<dim3(32, 3), dim3(256), 0, stream>>>(x, qdn, kdn, vdn, t1);
    gemm_loraup_k<<<dim3(2, 24, 3), dim3(256), 0, stream>>>(t1, qup, kup, vup, qf, kf, vf);

    // 3) IP projections fused: [128][3072] = img @ W_ip^T (split-K=8 x 2 matrices)
    gemm_ip_k<<<dim3(1, 24, 16), dim3(256), 0, stream>>>(img, Wkip, Wvip, kipf, vipf);

    // 4) norm (+rope) -> head-major bf16 (Q pre-scaled); V transposes
    norm_qk_k<<<dim3(13824, 2), dim3(256), 0, stream>>>(qf, kf, nqw, nkw, rc, rsn, Qb, Kb, QSCALE);
    norm_ip_k<<<dim3(768), dim3(256), 0, stream>>>(kipf, Kipb);
    transpose_v_k<<<dim3(36, 24), dim3(256), 0, stream>>>(vf, Vt, S_TOT);
    transpose_v_k<<<dim3(2, 24),  dim3(256), 0, stream>>>(vipf, Vipt, TIP);

    // 5) attention: main split-K (3 chunks of 24 key-tiles, partial store), IP direct, merge
    attn_k<<<dim3(36, 24, KS), dim3(256), 0, stream>>>(Qb, Kb, Vt, nullptr, opart, ml, S_TOT, 64, 24, 1);
    attn_k<<<dim3(36, 24, 1),  dim3(256), 0, stream>>>(Qb, Kipb, Vipt, ipo, nullptr, nullptr, TIP, 0, 4, 0);
    merge_k<<<dim3(13824), dim3(256), 0, stream>>>(opart, ml, ipo, outf);
}

// Round 4
// 972.715 us; speedup vs baseline: 1.9729x; 1.2744x over previous
//
#include <hip/hip_runtime.h>

#define S_TOT 2304
#define D_TOT 3072
#define NH    24
#define HD    128
#define BLK_R 2048
#define TIP   128
#define DIP   4096
#define KS    3      // attention split-K chunks (per = 24 key-tiles)

typedef __attribute__((ext_vector_type(4))) float f4;
typedef __attribute__((ext_vector_type(8))) short bh8;
typedef unsigned short u16;
typedef unsigned int   u32;
typedef unsigned long long u64;

__device__ __forceinline__ u16 f2bf(float f) {
    u32 u = __float_as_uint(f);
    u32 r = (u + 0x7fffu + ((u >> 16) & 1u)) >> 16;
    return (u16)r;
}
__device__ __forceinline__ uint4 pack8u(float4 a, float4 b) {
    uint4 u;
    u.x = (u32)f2bf(a.x) | ((u32)f2bf(a.y) << 16);
    u.y = (u32)f2bf(a.z) | ((u32)f2bf(a.w) << 16);
    u.z = (u32)f2bf(b.x) | ((u32)f2bf(b.y) << 16);
    u.w = (u32)f2bf(b.z) | ((u32)f2bf(b.w) << 16);
    return u;
}
__device__ __forceinline__ bh8 pack8v(float4 a, float4 b) {
    bh8 v;
    v[0] = (short)f2bf(a.x); v[1] = (short)f2bf(a.y);
    v[2] = (short)f2bf(a.z); v[3] = (short)f2bf(a.w);
    v[4] = (short)f2bf(b.x); v[5] = (short)f2bf(b.y);
    v[6] = (short)f2bf(b.z); v[7] = (short)f2bf(b.w);
    return v;
}

// ---------------- GEMM body: C[M][N] (+)= A[M][K] @ B[N][K]^T + bias ----------------
__device__ __forceinline__ void gemm_body(const float* __restrict__ A, const float* __restrict__ B,
                                          const float* __restrict__ bias, float* __restrict__ C,
                                          int M, int N, int K, int mode, int kbeg, int kend,
                                          u16* As, u16* Bs)
{
    const int tid  = threadIdx.x;
    const int wv   = tid >> 6;
    const int lane = tid & 63;
    const int quad = lane >> 4;
    const int l16  = lane & 15;
    const int wm   = (wv >> 1) << 6;
    const int wn   = (wv & 1) << 6;
    const int m0   = blockIdx.x << 7;
    const int n0   = blockIdx.y << 7;

    f4 acc[4][4] = {};

    for (int k0 = kbeg; k0 < kend; k0 += 64) {
#pragma unroll
        for (int p = 0; p < 4; ++p) {
            int idx = (p << 11) + (tid << 3);
            int r = idx >> 6, c = idx & 63;
            const float* ap = A + (size_t)(m0 + r) * K + k0 + c;
            *(uint4*)(&As[idx]) = pack8u(*(const float4*)ap, *(const float4*)(ap + 4));
            const float* bp = B + (size_t)(n0 + r) * K + k0 + c;
            *(uint4*)(&Bs[idx]) = pack8u(*(const float4*)bp, *(const float4*)(bp + 4));
        }
        __syncthreads();
#pragma unroll
        for (int kk = 0; kk < 2; ++kk) {
            bh8 a[4], b[4];
#pragma unroll
            for (int i = 0; i < 4; ++i)
                a[i] = *(const bh8*)(&As[(wm + (i << 4) + l16) * 64 + (kk << 5) + (quad << 3)]);
#pragma unroll
            for (int i = 0; i < 4; ++i)
                b[i] = *(const bh8*)(&Bs[(wn + (i << 4) + l16) * 64 + (kk << 5) + (quad << 3)]);
#pragma unroll
            for (int mt = 0; mt < 4; ++mt)
#pragma unroll
                for (int nt = 0; nt < 4; ++nt)
                    acc[mt][nt] = __builtin_amdgcn_mfma_f32_16x16x32_bf16(a[mt], b[nt], acc[mt][nt], 0, 0, 0);
        }
        __syncthreads();
    }
#pragma unroll
    for (int mt = 0; mt < 4; ++mt) {
#pragma unroll
        for (int nt = 0; nt < 4; ++nt) {
            int n = n0 + wn + (nt << 4) + l16;
            float bs = bias ? bias[n] : 0.0f;
#pragma unroll
            for (int r = 0; r < 4; ++r) {
                int m = m0 + wm + (mt << 4) + (quad << 2) + r;
                size_t o = (size_t)m * N + n;
                float v = acc[mt][nt][r] + bs;
                if (mode == 0)      C[o] = v;
                else if (mode == 1) C[o] += v;
                else                atomicAdd(&C[o], v);
            }
        }
    }
}

// QKV fused: blockIdx.z selects (W, bias, C). grid (18,24,3).
__global__ __launch_bounds__(256)
void gemm_qkv_k(const float* __restrict__ x,
                const float* __restrict__ Wq, const float* __restrict__ bq, float* __restrict__ qf,
                const float* __restrict__ Wk, const float* __restrict__ bk, float* __restrict__ kf,
                const float* __restrict__ Wv, const float* __restrict__ bv, float* __restrict__ vf)
{
    __shared__ u16 As[128 * 64];
    __shared__ u16 Bs[128 * 64];
    int z = blockIdx.z;
    const float* B  = z == 0 ? Wq : (z == 1 ? Wk : Wv);
    const float* bi = z == 0 ? bq : (z == 1 ? bk : bv);
    float*       C  = z == 0 ? qf : (z == 1 ? kf : vf);
    gemm_body(x, B, bi, C, S_TOT, D_TOT, D_TOT, 0, 0, D_TOT, As, Bs);
}

// LoRA up fused: grid (2,24,3).
__global__ __launch_bounds__(256)
void gemm_loraup_k(const float* __restrict__ t1,
                   const float* __restrict__ qup, const float* __restrict__ kup, const float* __restrict__ vup,
                   float* __restrict__ qf, float* __restrict__ kf, float* __restrict__ vf)
{
    __shared__ u16 As[128 * 64];
    __shared__ u16 Bs[128 * 64];
    int z = blockIdx.z;
    const float* A = t1 + (size_t)z * 32768;
    const float* B = z == 0 ? qup : (z == 1 ? kup : vup);
    float*       C = (z == 0 ? qf : (z == 1 ? kf : vf)) + (size_t)BLK_R * D_TOT;
    gemm_body(A, B, nullptr, C, 256, D_TOT, 128, 1, 0, 128, As, Bs);
}

// IP projections fused: grid (1,24,16).
__global__ __launch_bounds__(256)
void gemm_ip_k(const float* __restrict__ img,
               const float* __restrict__ Wkip, const float* __restrict__ Wvip,
               float* __restrict__ kipf, float* __restrict__ vipf)
{
    __shared__ u16 As[128 * 64];
    __shared__ u16 Bs[128 * 64];
    int z = blockIdx.z;
    int sel = z >> 3, cz = z & 7;
    const float* B = sel ? Wvip : Wkip;
    float*       C = sel ? vipf : kipf;
    gemm_body(img, B, nullptr, C, TIP, D_TOT, DIP, 2, cz * 512, cz * 512 + 512, As, Bs);
}

// ---------------- LoRA down fused: grid (32,3) ----------------
__global__ __launch_bounds__(256)
void lora_down_k(const float* __restrict__ X,
                 const float* __restrict__ qdn, const float* __restrict__ kdn, const float* __restrict__ vdn,
                 float* __restrict__ t1)
{
    int y = blockIdx.y;
    const float* Dwn = y == 0 ? qdn : (y == 1 ? kdn : vdn);
    float* T1 = t1 + (size_t)y * 32768;
    int wv = threadIdx.x >> 6, lane = threadIdx.x & 63;
    int quad = lane >> 4, l16 = lane & 15;
    int gw = blockIdx.x * 4 + wv;          // 0..127
    int mt = gw >> 3, nt = gw & 7;
    const float* ap = X + (size_t)(BLK_R + (mt << 4) + l16) * D_TOT + (quad << 3);
    const float* bp = Dwn + (size_t)((nt << 4) + l16) * D_TOT + (quad << 3);
    f4 acc = {};
    for (int c = 0; c < 96; ++c) {
        bh8 a = pack8v(*(const float4*)(ap + (c << 5)), *(const float4*)(ap + (c << 5) + 4));
        bh8 b = pack8v(*(const float4*)(bp + (c << 5)), *(const float4*)(bp + (c << 5) + 4));
        acc = __builtin_amdgcn_mfma_f32_16x16x32_bf16(a, b, acc, 0, 0, 0);
    }
#pragma unroll
    for (int r = 0; r < 4; ++r) {
        int s  = (mt << 4) + (quad << 2) + r;
        int rr = (nt << 4) + l16;
        T1[(size_t)s * 128 + rr] = acc[r];
    }
}

// ---------------- RMSNorm (+f32 weight) + optional RoPE body ----------------
template <int ROPE>
__device__ __forceinline__ void norm_rope_body(const float* __restrict__ X, const float* __restrict__ w,
                                               const float* __restrict__ ct, const float* __restrict__ st,
                                               u16* __restrict__ Out, int Slen, float omul, int g, int lane)
{
    int s = g / NH, h = g % NH;
    const float* xp = X + (size_t)s * D_TOT + (h << 7) + (lane << 1);
    float2 xv = *(const float2*)xp;
    float ss = xv.x * xv.x + xv.y * xv.y;
#pragma unroll
    for (int off = 1; off <= 32; off <<= 1) ss += __shfl_xor(ss, off);
    float invr = rsqrtf(ss * (1.0f / 128.0f) + 1e-5f);
    float a = xv.x * invr, b = xv.y * invr;
    if (w) { a *= w[lane << 1]; b *= w[(lane << 1) + 1]; }
    float o0 = a, o1 = b;
    if (ROPE) {
        float c0 = ct[(size_t)s * HD + (lane << 1)], c1 = ct[(size_t)s * HD + (lane << 1) + 1];
        float n0 = st[(size_t)s * HD + (lane << 1)], n1 = st[(size_t)s * HD + (lane << 1) + 1];
        o0 = a * c0 - b * n0;
        o1 = b * c1 + a * n1;
    }
    o0 *= omul; o1 *= omul;
    size_t oo = ((size_t)h * Slen + s) * HD + (lane << 1);
    u32 pack = (u32)f2bf(o0) | ((u32)f2bf(o1) << 16);
    *(u32*)(&Out[oo]) = pack;
}

// Q and K fused: grid (13824, 2). y=0: Q (pre-scaled), y=1: K.
__global__ __launch_bounds__(256)
void norm_qk_k(const float* __restrict__ qf, const float* __restrict__ kf,
               const float* __restrict__ nqw, const float* __restrict__ nkw,
               const float* __restrict__ ct, const float* __restrict__ st,
               u16* __restrict__ Qb, u16* __restrict__ Kb, float qscale)
{
    int g = blockIdx.x * 4 + (threadIdx.x >> 6);
    int lane = threadIdx.x & 63;
    if (blockIdx.y == 0)
        norm_rope_body<1>(qf, nqw, ct, st, Qb, S_TOT, qscale, g, lane);
    else
        norm_rope_body<1>(kf, nkw, ct, st, Kb, S_TOT, 1.0f, g, lane);
}

__global__ __launch_bounds__(256)
void norm_ip_k(const float* __restrict__ X, u16* __restrict__ Out)
{
    int g = blockIdx.x * 4 + (threadIdx.x >> 6);
    int lane = threadIdx.x & 63;
    norm_rope_body<0>(X, nullptr, nullptr, nullptr, Out, TIP, 1.0f, g, lane);
}

// ---------------- V transpose: f32 [Slen][3072] -> bf16 Vt[H][HD][Slen] ----------------
__global__ __launch_bounds__(256)
void transpose_v_k(const float* __restrict__ V, u16* __restrict__ Vt, int Slen)
{
    __shared__ u16 tile[64][130];
    int h = blockIdx.y;
    int s0 = blockIdx.x << 6;
    int tid = threadIdx.x;
#pragma unroll
    for (int p = 0; p < 32; ++p) {
        int flat = (p << 8) + tid;
        int si = flat >> 7, d = flat & 127;
        tile[si][d] = f2bf(V[(size_t)(s0 + si) * D_TOT + (h << 7) + d]);
    }
    __syncthreads();
#pragma unroll
    for (int p = 0; p < 32; ++p) {
        int flat = (p << 8) + tid;
        int d = flat >> 6, si = flat & 63;
        Vt[((size_t)(h << 7) + d) * Slen + s0 + si] = tile[si][d];
    }
}

// ---------------- MFMA flash attention, split-K, block-cooperative LDS K/V ----------------
// Qb [H][S_TOT][128] (pre-scaled), Kb [H][Lk][128], Vt [H][128][Lk].
// 1-D grid with XCD-chunked swizzle (nblk % 8 == 0). f -> (qt, h, ch).
// K/V tiles staged once per block into double-buffered LDS (padded strides 136/40),
// register-prefetched one tile ahead; one __syncthreads per key tile.
// mode 0: normalized write to Out. mode 1: partial O to Opart + (m,l) to Ml.
__global__ __launch_bounds__(256)
void attn_k(const u16* __restrict__ Qb, const u16* __restrict__ Kb,
            const u16* __restrict__ Vt, float* __restrict__ Out,
            float* __restrict__ Opart, float2* __restrict__ Ml,
            int Lk, int cond_start, int per, int mode, int nqt, int nblk)
{
    __shared__ __align__(16) u16 Ks[2][32 * 136];   // [key][d], stride 136
    __shared__ __align__(16) u16 Vs[2][128 * 40];   // [d][key], stride 40
    __shared__ __align__(16) u16 Pl[4][16 * 40];    // per-wave P tile

    // XCD-chunked bijective swizzle: consecutive f on one XCD -> K/V L2 locality
    const int bid = blockIdx.x;
    const int f = (bid & 7) * (nblk >> 3) + (bid >> 3);
    const int qt = f % nqt;
    const int h  = (f / nqt) % NH;
    const int ch = f / (nqt * NH);

    const int tid = threadIdx.x;
    const int wv = tid >> 6;
    const int lane = tid & 63;
    const int quad = lane >> 4, l16 = lane & 15;
    const int sb = (qt << 6) + (wv << 4);

    bh8 qf[4];
    const u16* qp = Qb + ((size_t)h * S_TOT + sb + l16) * HD + (quad << 3);
#pragma unroll
    for (int c = 0; c < 4; ++c) qf[c] = *(const bh8*)(qp + (c << 5));

    f4 o[8] = {};
    float mrow[4]  = {-1e30f, -1e30f, -1e30f, -1e30f};
    float lpart[4] = {0.f, 0.f, 0.f, 0.f};
    u16* pl = &Pl[wv][0];

    const int kt0 = (sb >= BLK_R) ? cond_start : 0;   // block-uniform (64-row q-tiles)
    const int ktN = Lk >> 5;
    int kt_lo = ch * per;       if (kt0 > kt_lo) kt_lo = kt0;
    int kt_hi = ch * per + per; if (ktN < kt_hi) kt_hi = ktN;

    if (kt_lo < kt_hi) {
        // staging geometry: K tile 32x128 (thread: row=tid>>3, col=(tid&7)*16),
        //                   V tile 128x32 (thread: row=tid>>1, col=(tid&1)*16)
        const int rowK = tid >> 3, colK = (tid & 7) << 4;
        const int rowV = tid >> 1, colV = (tid & 1) << 4;
        const u16* ksrc0 = Kb + ((size_t)h * Lk + rowK) * HD + colK;
        const u16* vsrc0 = Vt + (((size_t)h << 7) + rowV) * Lk + colV;
        u16* kdst = &Ks[0][0] + rowK * 136 + colK;
        u16* vdst = &Vs[0][0] + rowV * 40 + colV;

        { // prologue: stage kt_lo into buffer 0
            const u16* ks = ksrc0 + ((size_t)kt_lo << 5) * HD;
            const u16* vs = vsrc0 + ((size_t)kt_lo << 5);
            uint4 a = *(const uint4*)ks, b = *(const uint4*)(ks + 8);
            uint4 c = *(const uint4*)vs, d = *(const uint4*)(vs + 8);
            *(uint4*)kdst = a; *(uint4*)(kdst + 8) = b;
            *(uint4*)vdst = c; *(uint4*)(vdst + 8) = d;
        }
        __syncthreads();

        int p = 0;
        for (int kt = kt_lo; kt < kt_hi; ++kt) {
            // prefetch next tile into registers (block-uniform branch)
            uint4 pk0 = {}, pk1 = {}, pv0 = {}, pv1 = {};
            const bool pf = (kt + 1 < kt_hi);
            if (pf) {
                const u16* ks = ksrc0 + ((size_t)(kt + 1) << 5) * HD;
                const u16* vs = vsrc0 + ((size_t)(kt + 1) << 5);
                pk0 = *(const uint4*)ks; pk1 = *(const uint4*)(ks + 8);
                pv0 = *(const uint4*)vs; pv1 = *(const uint4*)(vs + 8);
            }
            const u16* kb = &Ks[p][0];
            const u16* vb = &Vs[p][0];

            f4 s0 = {}, s1 = {};
            __builtin_amdgcn_s_setprio(1);
#pragma unroll
            for (int c = 0; c < 4; ++c) {
                bh8 k0 = *(const bh8*)(kb + l16 * 136 + (c << 5) + (quad << 3));
                bh8 k1 = *(const bh8*)(kb + (16 + l16) * 136 + (c << 5) + (quad << 3));
                s0 = __builtin_amdgcn_mfma_f32_16x16x32_bf16(qf[c], k0, s0, 0, 0, 0);
                s1 = __builtin_amdgcn_mfma_f32_16x16x32_bf16(qf[c], k1, s1, 0, 0, 0);
            }
            __builtin_amdgcn_s_setprio(0);

            float mx[4];
#pragma unroll
            for (int r = 0; r < 4; ++r) mx[r] = fmaxf(s0[r], s1[r]);
#pragma unroll
            for (int off = 1; off <= 8; off <<= 1)
#pragma unroll
                for (int r = 0; r < 4; ++r) mx[r] = fmaxf(mx[r], __shfl_xor(mx[r], off));

            int grow = 0;
#pragma unroll
            for (int r = 0; r < 4; ++r) grow |= (mx[r] > mrow[r]) ? 1 : 0;
            if (__any(grow)) {
#pragma unroll
                for (int r = 0; r < 4; ++r) {
                    float mn = fmaxf(mrow[r], mx[r]);
                    float al = exp2f(mrow[r] - mn);
                    mrow[r] = mn;
                    lpart[r] *= al;
#pragma unroll
                    for (int dt = 0; dt < 8; ++dt) o[dt][r] *= al;
                }
            }
            float p0[4], p1[4];
#pragma unroll
            for (int r = 0; r < 4; ++r) {
                p0[r] = exp2f(s0[r] - mrow[r]);
                p1[r] = exp2f(s1[r] - mrow[r]);
                lpart[r] += p0[r] + p1[r];
            }
#pragma unroll
            for (int r = 0; r < 4; ++r) {
                pl[((quad << 2) + r) * 40 + l16]      = f2bf(p0[r]);
                pl[((quad << 2) + r) * 40 + 16 + l16] = f2bf(p1[r]);
            }
            bh8 pa = *(const bh8*)(pl + l16 * 40 + (quad << 3));
            __builtin_amdgcn_s_setprio(1);
#pragma unroll
            for (int dt = 0; dt < 8; ++dt) {
                bh8 v = *(const bh8*)(vb + ((dt << 4) + l16) * 40 + (quad << 3));
                o[dt] = __builtin_amdgcn_mfma_f32_16x16x32_bf16(pa, v, o[dt], 0, 0, 0);
            }
            __builtin_amdgcn_s_setprio(0);

            // write prefetched tile into the other buffer (readers of it passed
            // the barrier that ended the previous iteration)
            if (pf) {
                u16* kd = kdst + (p ^ 1) * (32 * 136);
                u16* vd = vdst + (p ^ 1) * (128 * 40);
                *(uint4*)kd = pk0; *(uint4*)(kd + 8) = pk1;
                *(uint4*)vd = pv0; *(uint4*)(vd + 8) = pv1;
            }
            __syncthreads();
            p ^= 1;
        }
    }

    // final cross-lane row-sum reduction (once)
#pragma unroll
    for (int off = 1; off <= 8; off <<= 1)
#pragma unroll
        for (int r = 0; r < 4; ++r) lpart[r] += __shfl_xor(lpart[r], off);

    if (mode == 0) {
        float inv[4];
#pragma unroll
        for (int r = 0; r < 4; ++r) inv[r] = 1.0f / lpart[r];
#pragma unroll
        for (int dt = 0; dt < 8; ++dt) {
#pragma unroll
            for (int r = 0; r < 4; ++r) {
                int row = sb + (quad << 2) + r;
                int col = (h << 7) + (dt << 4) + l16;
                Out[(size_t)row * D_TOT + col] = o[dt][r] * inv[r];
            }
        }
    } else {
        const size_t cb = ((size_t)ch * NH + h) * S_TOT;
#pragma unroll
        for (int dt = 0; dt < 8; ++dt) {
#pragma unroll
            for (int r = 0; r < 4; ++r) {
                int row = sb + (quad << 2) + r;
                Opart[(cb + row) * 128 + (dt << 4) + l16] = o[dt][r];
            }
        }
        if (l16 == 0) {
#pragma unroll
            for (int r = 0; r < 4; ++r) {
                int row = sb + (quad << 2) + r;
                Ml[cb + row] = (float2){mrow[r], lpart[r]};
            }
        }
    }
}

// ---------------- merge: Out = (Σ_c w_c O_c)/(Σ_c w_c l_c) + ipo ----------------
__global__ __launch_bounds__(256)
void merge_k(const float* __restrict__ Opart, const float2* __restrict__ Ml,
             const float* __restrict__ ipo, float* __restrict__ Out)
{
    int g = blockIdx.x * 4 + (threadIdx.x >> 6);   // (h,s) row id
    int lane = threadIdx.x & 63;
    int h = g / S_TOT;
    int s = g - h * S_TOT;
    float m[KS], l[KS];
#pragma unroll
    for (int c = 0; c < KS; ++c) {
        float2 ml = Ml[((size_t)c * NH + h) * S_TOT + s];
        m[c] = ml.x; l[c] = ml.y;
    }
    float M = m[0];
#pragma unroll
    for (int c = 1; c < KS; ++c) M = fmaxf(M, m[c]);
    float w[KS], lt = 0.f;
#pragma unroll
    for (int c = 0; c < KS; ++c) { w[c] = exp2f(m[c] - M); lt += w[c] * l[c]; }
    float inv = 1.0f / lt;
    float ax = 0.f, ay = 0.f;
#pragma unroll
    for (int c = 0; c < KS; ++c) {
        const float2 ov = *(const float2*)&Opart[(((size_t)c * NH + h) * S_TOT + s) * 128 + (lane << 1)];
        ax += w[c] * ov.x; ay += w[c] * ov.y;
    }
    size_t oidx = (size_t)s * D_TOT + (h << 7) + (lane << 1);
    float2 ip = *(const float2*)&ipo[oidx];
    float2 res = {ax * inv + ip.x, ay * inv + ip.y};
    *(float2*)&Out[oidx] = res;
}

// ---------------- workspace layout (byte offsets); ws >= 215 MB verified ----------------
static const u64 B_OP   = 0;           // f32 [3][24][2304][128] (reuses dead qf/kf/vf region)
static const u64 B_QF   = 0;
static const u64 B_KF   = 28311552;
static const u64 B_VF   = 56623104;
static const u64 B_KIPF = 84934656;
static const u64 B_VIPF = 86507520;
static const u64 B_T1   = 88080384;
static const u64 B_QB   = 88473600;
static const u64 B_KB   = 102629376;
static const u64 B_VT   = 116785152;
static const u64 B_KIPB = 130940928;
static const u64 B_VIPT = 131727360;
static const u64 B_ML   = 132513792;
static const u64 B_IPO  = 134217728;

extern "C" void kernel_launch(void* const* d_in, const int* in_sizes, int n_in,
                              void* d_out, int out_size, void* d_ws, size_t ws_size,
                              hipStream_t stream) {
    (void)in_sizes; (void)n_in; (void)out_size; (void)ws_size;
    const float* x    = (const float*)d_in[0];
    const float* img  = (const float*)d_in[1];
    const float* rc   = (const float*)d_in[2];
    const float* rsn  = (const float*)d_in[3];
    const float* Wq   = (const float*)d_in[4];
    const float* bq   = (const float*)d_in[5];
    const float* Wk   = (const float*)d_in[6];
    const float* bk   = (const float*)d_in[7];
    const float* Wv   = (const float*)d_in[8];
    const float* bv   = (const float*)d_in[9];
    const float* qdn  = (const float*)d_in[10];
    const float* qup  = (const float*)d_in[11];
    const float* kdn  = (const float*)d_in[12];
    const float* kup  = (const float*)d_in[13];
    const float* vdn  = (const float*)d_in[14];
    const float* vup  = (const float*)d_in[15];
    const float* nqw  = (const float*)d_in[16];
    const float* nkw  = (const float*)d_in[17];
    const float* Wkip = (const float*)d_in[18];
    const float* Wvip = (const float*)d_in[19];

    float*  qf   = (float*)((char*)d_ws + B_QF);
    float*  kf   = (float*)((char*)d_ws + B_KF);
    float*  vf   = (float*)((char*)d_ws + B_VF);
    float*  kipf = (float*)((char*)d_ws + B_KIPF);
    float*  vipf = (float*)((char*)d_ws + B_VIPF);
    float*  t1   = (float*)((char*)d_ws + B_T1);
    u16*    Qb   = (u16*)((char*)d_ws + B_QB);
    u16*    Kb   = (u16*)((char*)d_ws + B_KB);
    u16*    Vt   = (u16*)((char*)d_ws + B_VT);
    u16*    Kipb = (u16*)((char*)d_ws + B_KIPB);
    u16*    Vipt = (u16*)((char*)d_ws + B_VIPT);
    float*  opart= (float*)((char*)d_ws + B_OP);
    float2* ml   = (float2*)((char*)d_ws + B_ML);
    float*  ipo  = (float*)((char*)d_ws + B_IPO);
    float*  outf = (float*)d_out;

    const float QSCALE = 0.08838834764831845f * 1.4426950408889634f;  // 1/sqrt(128) * log2(e)

    hipMemsetAsync((char*)d_ws + B_KIPF, 0, 2 * 1572864, stream);

    gemm_qkv_k<<<dim3(18, 24, 3), dim3(256), 0, stream>>>(x, Wq, bq, qf, Wk, bk, kf, Wv, bv, vf);

    lora_down_k<<<dim3(32, 3), dim3(256), 0, stream>>>(x, qdn, kdn, vdn, t1);
    gemm_loraup_k<<<dim3(2, 24, 3), dim3(256), 0, stream>>>(t1, qup, kup, vup, qf, kf, vf);

    gemm_ip_k<<<dim3(1, 24, 16), dim3(256), 0, stream>>>(img, Wkip, Wvip, kipf, vipf);

    norm_qk_k<<<dim3(13824, 2), dim3(256), 0, stream>>>(qf, kf, nqw, nkw, rc, rsn, Qb, Kb, QSCALE);
    norm_ip_k<<<dim3(768), dim3(256), 0, stream>>>(kipf, Kipb);
    transpose_v_k<<<dim3(36, 24), dim3(256), 0, stream>>>(vf, Vt, S_TOT);
    transpose_v_k<<<dim3(2, 24),  dim3(256), 0, stream>>>(vipf, Vipt, TIP);

    // attention: main split-K (2592 blocks, partial store), IP direct (864), merge
    attn_k<<<dim3(2592), dim3(256), 0, stream>>>(Qb, Kb, Vt, nullptr, opart, ml, S_TOT, 64, 24, 1, 36, 2592);
    attn_k<<<dim3(864),  dim3(256), 0, stream>>>(Qb, Kipb, Vipt, ipo, nullptr, nullptr, TIP, 0, 4, 0, 36, 864);
    merge_k<<<dim3(13824), dim3(256), 0, stream>>>(opart, ml, ipo, outf);
}

// Round 5
// 801.646 us; speedup vs baseline: 2.3939x; 1.2134x over previous
//
#include <hip/hip_runtime.h>

#define S_TOT 2304
#define D_TOT 3072
#define NH    24
#define HD    128
#define BLK_R 2048
#define TIP   128
#define DIP   4096
#define KS    3      // attention split-K chunks (per = 24 key-tiles)

typedef __attribute__((ext_vector_type(4))) float f4;
typedef __attribute__((ext_vector_type(8))) short bh8;
typedef unsigned short u16;
typedef unsigned int   u32;
typedef unsigned long long u64;

__device__ __forceinline__ u16 f2bf(float f) {
    u32 u = __float_as_uint(f);
    u32 r = (u + 0x7fffu + ((u >> 16) & 1u)) >> 16;
    return (u16)r;
}
__device__ __forceinline__ uint4 pack8u(float4 a, float4 b) {
    uint4 u;
    u.x = (u32)f2bf(a.x) | ((u32)f2bf(a.y) << 16);
    u.y = (u32)f2bf(a.z) | ((u32)f2bf(a.w) << 16);
    u.z = (u32)f2bf(b.x) | ((u32)f2bf(b.y) << 16);
    u.w = (u32)f2bf(b.z) | ((u32)f2bf(b.w) << 16);
    return u;
}
__device__ __forceinline__ bh8 pack8v(float4 a, float4 b) {
    bh8 v;
    v[0] = (short)f2bf(a.x); v[1] = (short)f2bf(a.y);
    v[2] = (short)f2bf(a.z); v[3] = (short)f2bf(a.w);
    v[4] = (short)f2bf(b.x); v[5] = (short)f2bf(b.y);
    v[6] = (short)f2bf(b.z); v[7] = (short)f2bf(b.w);
    return v;
}

// ---------------- f32 -> bf16 bulk convert: y selects (src,dst,count) ----------------
// y=0: x [2304*3072]; y=1..3: W [3072*3072]. counts in units of 8 elements.
__global__ __launch_bounds__(256)
void conv_bf16_k(const float* __restrict__ s0, u16* __restrict__ d0, int n0c,
                 const float* __restrict__ s1, u16* __restrict__ d1,
                 const float* __restrict__ s2, u16* __restrict__ d2,
                 const float* __restrict__ s3, u16* __restrict__ d3, int n1c)
{
    int y = blockIdx.y;
    const float* s = y == 0 ? s0 : (y == 1 ? s1 : (y == 2 ? s2 : s3));
    u16*         d = y == 0 ? d0 : (y == 1 ? d1 : (y == 2 ? d2 : d3));
    int n = (y == 0) ? n0c : n1c;
    int stride = gridDim.x * blockDim.x;
    for (int i = blockIdx.x * blockDim.x + threadIdx.x; i < n; i += stride) {
        float4 a = *(const float4*)(s + (size_t)i * 8);
        float4 b = *(const float4*)(s + (size_t)i * 8 + 4);
        *(uint4*)(d + (size_t)i * 8) = pack8u(a, b);
    }
}

// ---------------- QKV GEMM, bf16 inputs, m97 structure ----------------
// C[M][N] = A[M][K] @ B[N][K]^T + bias. A=xb bf16, B=Wb[z] bf16.
// 128x128 tile, BK=64, 4 waves, global_load_lds width-16 staging (linear LDS),
// 2 barriers per K-step.
__global__ __launch_bounds__(256)
void gemm_qkv_bf16_k(const u16* __restrict__ xb, const u16* __restrict__ Wb,
                     const float* __restrict__ bq, const float* __restrict__ bk,
                     const float* __restrict__ bv,
                     float* __restrict__ qf, float* __restrict__ kf, float* __restrict__ vf)
{
    __shared__ __align__(16) u16 As[128 * 64];
    __shared__ __align__(16) u16 Bs[128 * 64];
    const int z = blockIdx.z;
    const u16* Bw = Wb + (size_t)z * D_TOT * D_TOT;
    const float* bias = z == 0 ? bq : (z == 1 ? bk : bv);
    float* C = z == 0 ? qf : (z == 1 ? kf : vf);

    const int tid  = threadIdx.x;
    const int wv   = tid >> 6;
    const int lane = tid & 63;
    const int quad = lane >> 4;
    const int l16  = lane & 15;
    const int wm   = (wv >> 1) << 6;
    const int wn   = (wv & 1) << 6;
    const int m0   = blockIdx.x << 7;
    const int n0   = blockIdx.y << 7;

    // staging geometry: 16 segments of 1024 B (8 rows x 64 cols bf16) per tile;
    // wave w stages segs {w, 4+w, 8+w, 12+w}; lane covers 16 B (8 bf16).
    const int srow = lane >> 3;          // 0..7 within segment
    const int scol = (lane & 7) << 3;    // 0,8,..,56

    f4 acc[4][4] = {};

    for (int k0 = 0; k0 < D_TOT; k0 += 64) {
#pragma unroll
        for (int j = 0; j < 4; ++j) {
            int seg = (j << 2) + wv;
            int r = (seg << 3) + srow;
            const u16* ga = xb + (size_t)(m0 + r) * D_TOT + k0 + scol;
            const u16* gb = Bw + (size_t)(n0 + r) * D_TOT + k0 + scol;
            __builtin_amdgcn_global_load_lds((const __attribute__((address_space(1))) void*)ga,
                                             (__attribute__((address_space(3))) void*)(&As[seg << 9]),
                                             16, 0, 0);
            __builtin_amdgcn_global_load_lds((const __attribute__((address_space(1))) void*)gb,
                                             (__attribute__((address_space(3))) void*)(&Bs[seg << 9]),
                                             16, 0, 0);
        }
        __syncthreads();
#pragma unroll
        for (int kk = 0; kk < 2; ++kk) {
            bh8 a[4], b[4];
#pragma unroll
            for (int i = 0; i < 4; ++i)
                a[i] = *(const bh8*)(&As[(wm + (i << 4) + l16) * 64 + (kk << 5) + (quad << 3)]);
#pragma unroll
            for (int i = 0; i < 4; ++i)
                b[i] = *(const bh8*)(&Bs[(wn + (i << 4) + l16) * 64 + (kk << 5) + (quad << 3)]);
#pragma unroll
            for (int mt = 0; mt < 4; ++mt)
#pragma unroll
                for (int nt = 0; nt < 4; ++nt)
                    acc[mt][nt] = __builtin_amdgcn_mfma_f32_16x16x32_bf16(a[mt], b[nt], acc[mt][nt], 0, 0, 0);
        }
        __syncthreads();
    }
#pragma unroll
    for (int mt = 0; mt < 4; ++mt) {
#pragma unroll
        for (int nt = 0; nt < 4; ++nt) {
            int n = n0 + wn + (nt << 4) + l16;
            float bs = bias[n];
#pragma unroll
            for (int r = 0; r < 4; ++r) {
                int m = m0 + wm + (mt << 4) + (quad << 2) + r;
                C[(size_t)m * D_TOT + n] = acc[mt][nt][r] + bs;
            }
        }
    }
}

// ---------------- generic f32 GEMM body (kept for LoRA-up and IP projections) ----------------
__device__ __forceinline__ void gemm_body(const float* __restrict__ A, const float* __restrict__ B,
                                          const float* __restrict__ bias, float* __restrict__ C,
                                          int M, int N, int K, int mode, int kbeg, int kend,
                                          u16* As, u16* Bs)
{
    const int tid  = threadIdx.x;
    const int wv   = tid >> 6;
    const int lane = tid & 63;
    const int quad = lane >> 4;
    const int l16  = lane & 15;
    const int wm   = (wv >> 1) << 6;
    const int wn   = (wv & 1) << 6;
    const int m0   = blockIdx.x << 7;
    const int n0   = blockIdx.y << 7;

    f4 acc[4][4] = {};

    for (int k0 = kbeg; k0 < kend; k0 += 64) {
#pragma unroll
        for (int p = 0; p < 4; ++p) {
            int idx = (p << 11) + (tid << 3);
            int r = idx >> 6, c = idx & 63;
            const float* ap = A + (size_t)(m0 + r) * K + k0 + c;
            *(uint4*)(&As[idx]) = pack8u(*(const float4*)ap, *(const float4*)(ap + 4));
            const float* bp = B + (size_t)(n0 + r) * K + k0 + c;
            *(uint4*)(&Bs[idx]) = pack8u(*(const float4*)bp, *(const float4*)(bp + 4));
        }
        __syncthreads();
#pragma unroll
        for (int kk = 0; kk < 2; ++kk) {
            bh8 a[4], b[4];
#pragma unroll
            for (int i = 0; i < 4; ++i)
                a[i] = *(const bh8*)(&As[(wm + (i << 4) + l16) * 64 + (kk << 5) + (quad << 3)]);
#pragma unroll
            for (int i = 0; i < 4; ++i)
                b[i] = *(const bh8*)(&Bs[(wn + (i << 4) + l16) * 64 + (kk << 5) + (quad << 3)]);
#pragma unroll
            for (int mt = 0; mt < 4; ++mt)
#pragma unroll
                for (int nt = 0; nt < 4; ++nt)
                    acc[mt][nt] = __builtin_amdgcn_mfma_f32_16x16x32_bf16(a[mt], b[nt], acc[mt][nt], 0, 0, 0);
        }
        __syncthreads();
    }
#pragma unroll
    for (int mt = 0; mt < 4; ++mt) {
#pragma unroll
        for (int nt = 0; nt < 4; ++nt) {
            int n = n0 + wn + (nt << 4) + l16;
            float bs = bias ? bias[n] : 0.0f;
#pragma unroll
            for (int r = 0; r < 4; ++r) {
                int m = m0 + wm + (mt << 4) + (quad << 2) + r;
                size_t o = (size_t)m * N + n;
                float v = acc[mt][nt][r] + bs;
                if (mode == 0)      C[o] = v;
                else if (mode == 1) C[o] += v;
                else                atomicAdd(&C[o], v);
            }
        }
    }
}

// LoRA up fused: grid (2,24,3).
__global__ __launch_bounds__(256)
void gemm_loraup_k(const float* __restrict__ t1,
                   const float* __restrict__ qup, const float* __restrict__ kup, const float* __restrict__ vup,
                   float* __restrict__ qf, float* __restrict__ kf, float* __restrict__ vf)
{
    __shared__ u16 As[128 * 64];
    __shared__ u16 Bs[128 * 64];
    int z = blockIdx.z;
    const float* A = t1 + (size_t)z * 32768;
    const float* B = z == 0 ? qup : (z == 1 ? kup : vup);
    float*       C = (z == 0 ? qf : (z == 1 ? kf : vf)) + (size_t)BLK_R * D_TOT;
    gemm_body(A, B, nullptr, C, 256, D_TOT, 128, 1, 0, 128, As, Bs);
}

// IP projections fused: grid (1,24,16).
__global__ __launch_bounds__(256)
void gemm_ip_k(const float* __restrict__ img,
               const float* __restrict__ Wkip, const float* __restrict__ Wvip,
               float* __restrict__ kipf, float* __restrict__ vipf)
{
    __shared__ u16 As[128 * 64];
    __shared__ u16 Bs[128 * 64];
    int z = blockIdx.z;
    int sel = z >> 3, cz = z & 7;
    const float* B = sel ? Wvip : Wkip;
    float*       C = sel ? vipf : kipf;
    gemm_body(img, B, nullptr, C, TIP, D_TOT, DIP, 2, cz * 512, cz * 512 + 512, As, Bs);
}

// ---------------- LoRA down fused: grid (32,3); X is pre-converted bf16 ----------------
__global__ __launch_bounds__(256)
void lora_down_k(const u16* __restrict__ Xb,
                 const float* __restrict__ qdn, const float* __restrict__ kdn, const float* __restrict__ vdn,
                 float* __restrict__ t1)
{
    int y = blockIdx.y;
    const float* Dwn = y == 0 ? qdn : (y == 1 ? kdn : vdn);
    float* T1 = t1 + (size_t)y * 32768;
    int wv = threadIdx.x >> 6, lane = threadIdx.x & 63;
    int quad = lane >> 4, l16 = lane & 15;
    int gw = blockIdx.x * 4 + wv;          // 0..127
    int mt = gw >> 3, nt = gw & 7;
    const u16*   ap = Xb + (size_t)(BLK_R + (mt << 4) + l16) * D_TOT + (quad << 3);
    const float* bp = Dwn + (size_t)((nt << 4) + l16) * D_TOT + (quad << 3);
    f4 acc = {};
    for (int c = 0; c < 96; ++c) {
        bh8 a = *(const bh8*)(ap + (c << 5));
        bh8 b = pack8v(*(const float4*)(bp + (c << 5)), *(const float4*)(bp + (c << 5) + 4));
        acc = __builtin_amdgcn_mfma_f32_16x16x32_bf16(a, b, acc, 0, 0, 0);
    }
#pragma unroll
    for (int r = 0; r < 4; ++r) {
        int s  = (mt << 4) + (quad << 2) + r;
        int rr = (nt << 4) + l16;
        T1[(size_t)s * 128 + rr] = acc[r];
    }
}

// ---------------- RMSNorm (+f32 weight) + optional RoPE body ----------------
template <int ROPE>
__device__ __forceinline__ void norm_rope_body(const float* __restrict__ X, const float* __restrict__ w,
                                               const float* __restrict__ ct, const float* __restrict__ st,
                                               u16* __restrict__ Out, int Slen, float omul, int g, int lane)
{
    int s = g / NH, h = g % NH;
    const float* xp = X + (size_t)s * D_TOT + (h << 7) + (lane << 1);
    float2 xv = *(const float2*)xp;
    float ss = xv.x * xv.x + xv.y * xv.y;
#pragma unroll
    for (int off = 1; off <= 32; off <<= 1) ss += __shfl_xor(ss, off);
    float invr = rsqrtf(ss * (1.0f / 128.0f) + 1e-5f);
    float a = xv.x * invr, b = xv.y * invr;
    if (w) { a *= w[lane << 1]; b *= w[(lane << 1) + 1]; }
    float o0 = a, o1 = b;
    if (ROPE) {
        float c0 = ct[(size_t)s * HD + (lane << 1)], c1 = ct[(size_t)s * HD + (lane << 1) + 1];
        float n0 = st[(size_t)s * HD + (lane << 1)], n1 = st[(size_t)s * HD + (lane << 1) + 1];
        o0 = a * c0 - b * n0;
        o1 = b * c1 + a * n1;
    }
    o0 *= omul; o1 *= omul;
    size_t oo = ((size_t)h * Slen + s) * HD + (lane << 1);
    u32 pack = (u32)f2bf(o0) | ((u32)f2bf(o1) << 16);
    *(u32*)(&Out[oo]) = pack;
}

// Q and K fused: grid (13824, 2). y=0: Q (pre-scaled), y=1: K.
__global__ __launch_bounds__(256)
void norm_qk_k(const float* __restrict__ qf, const float* __restrict__ kf,
               const float* __restrict__ nqw, const float* __restrict__ nkw,
               const float* __restrict__ ct, const float* __restrict__ st,
               u16* __restrict__ Qb, u16* __restrict__ Kb, float qscale)
{
    int g = blockIdx.x * 4 + (threadIdx.x >> 6);
    int lane = threadIdx.x & 63;
    if (blockIdx.y == 0)
        norm_rope_body<1>(qf, nqw, ct, st, Qb, S_TOT, qscale, g, lane);
    else
        norm_rope_body<1>(kf, nkw, ct, st, Kb, S_TOT, 1.0f, g, lane);
}

__global__ __launch_bounds__(256)
void norm_ip_k(const float* __restrict__ X, u16* __restrict__ Out)
{
    int g = blockIdx.x * 4 + (threadIdx.x >> 6);
    int lane = threadIdx.x & 63;
    norm_rope_body<0>(X, nullptr, nullptr, nullptr, Out, TIP, 1.0f, g, lane);
}

// ---------------- V transpose: f32 [Slen][3072] -> bf16 Vt[H][HD][Slen] ----------------
__global__ __launch_bounds__(256)
void transpose_v_k(const float* __restrict__ V, u16* __restrict__ Vt, int Slen)
{
    __shared__ u16 tile[64][130];
    int h = blockIdx.y;
    int s0 = blockIdx.x << 6;
    int tid = threadIdx.x;
#pragma unroll
    for (int p = 0; p < 32; ++p) {
        int flat = (p << 8) + tid;
        int si = flat >> 7, d = flat & 127;
        tile[si][d] = f2bf(V[(size_t)(s0 + si) * D_TOT + (h << 7) + d]);
    }
    __syncthreads();
#pragma unroll
    for (int p = 0; p < 32; ++p) {
        int flat = (p << 8) + tid;
        int d = flat >> 6, si = flat & 63;
        Vt[((size_t)(h << 7) + d) * Slen + s0 + si] = tile[si][d];
    }
}

// ---------------- MFMA flash attention, split-K, block-cooperative LDS K/V ----------------
__global__ __launch_bounds__(256)
void attn_k(const u16* __restrict__ Qb, const u16* __restrict__ Kb,
            const u16* __restrict__ Vt, float* __restrict__ Out,
            float* __restrict__ Opart, float2* __restrict__ Ml,
            int Lk, int cond_start, int per, int mode, int nqt, int nblk)
{
    __shared__ __align__(16) u16 Ks[2][32 * 136];   // [key][d], stride 136
    __shared__ __align__(16) u16 Vs[2][128 * 40];   // [d][key], stride 40
    __shared__ __align__(16) u16 Pl[4][16 * 40];    // per-wave P tile

    const int bid = blockIdx.x;
    const int f = (bid & 7) * (nblk >> 3) + (bid >> 3);
    const int qt = f % nqt;
    const int h  = (f / nqt) % NH;
    const int ch = f / (nqt * NH);

    const int tid = threadIdx.x;
    const int wv = tid >> 6;
    const int lane = tid & 63;
    const int quad = lane >> 4, l16 = lane & 15;
    const int sb = (qt << 6) + (wv << 4);

    bh8 qf[4];
    const u16* qp = Qb + ((size_t)h * S_TOT + sb + l16) * HD + (quad << 3);
#pragma unroll
    for (int c = 0; c < 4; ++c) qf[c] = *(const bh8*)(qp + (c << 5));

    f4 o[8] = {};
    float mrow[4]  = {-1e30f, -1e30f, -1e30f, -1e30f};
    float lpart[4] = {0.f, 0.f, 0.f, 0.f};
    u16* pl = &Pl[wv][0];

    const int kt0 = (sb >= BLK_R) ? cond_start : 0;
    const int ktN = Lk >> 5;
    int kt_lo = ch * per;       if (kt0 > kt_lo) kt_lo = kt0;
    int kt_hi = ch * per + per; if (ktN < kt_hi) kt_hi = ktN;

    if (kt_lo < kt_hi) {
        const int rowK = tid >> 3, colK = (tid & 7) << 4;
        const int rowV = tid >> 1, colV = (tid & 1) << 4;
        const u16* ksrc0 = Kb + ((size_t)h * Lk + rowK) * HD + colK;
        const u16* vsrc0 = Vt + (((size_t)h << 7) + rowV) * Lk + colV;
        u16* kdst = &Ks[0][0] + rowK * 136 + colK;
        u16* vdst = &Vs[0][0] + rowV * 40 + colV;

        {
            const u16* ks = ksrc0 + ((size_t)kt_lo << 5) * HD;
            const u16* vs = vsrc0 + ((size_t)kt_lo << 5);
            uint4 a = *(const uint4*)ks, b = *(const uint4*)(ks + 8);
            uint4 c = *(const uint4*)vs, d = *(const uint4*)(vs + 8);
            *(uint4*)kdst = a; *(uint4*)(kdst + 8) = b;
            *(uint4*)vdst = c; *(uint4*)(vdst + 8) = d;
        }
        __syncthreads();

        int p = 0;
        for (int kt = kt_lo; kt < kt_hi; ++kt) {
            uint4 pk0 = {}, pk1 = {}, pv0 = {}, pv1 = {};
            const bool pf = (kt + 1 < kt_hi);
            if (pf) {
                const u16* ks = ksrc0 + ((size_t)(kt + 1) << 5) * HD;
                const u16* vs = vsrc0 + ((size_t)(kt + 1) << 5);
                pk0 = *(const uint4*)ks; pk1 = *(const uint4*)(ks + 8);
                pv0 = *(const uint4*)vs; pv1 = *(const uint4*)(vs + 8);
            }
            const u16* kb = &Ks[p][0];
            const u16* vb = &Vs[p][0];

            f4 s0 = {}, s1 = {};
            __builtin_amdgcn_s_setprio(1);
#pragma unroll
            for (int c = 0; c < 4; ++c) {
                bh8 k0 = *(const bh8*)(kb + l16 * 136 + (c << 5) + (quad << 3));
                bh8 k1 = *(const bh8*)(kb + (16 + l16) * 136 + (c << 5) + (quad << 3));
                s0 = __builtin_amdgcn_mfma_f32_16x16x32_bf16(qf[c], k0, s0, 0, 0, 0);
                s1 = __builtin_amdgcn_mfma_f32_16x16x32_bf16(qf[c], k1, s1, 0, 0, 0);
            }
            __builtin_amdgcn_s_setprio(0);

            float mx[4];
#pragma unroll
            for (int r = 0; r < 4; ++r) mx[r] = fmaxf(s0[r], s1[r]);
#pragma unroll
            for (int off = 1; off <= 8; off <<= 1)
#pragma unroll
                for (int r = 0; r < 4; ++r) mx[r] = fmaxf(mx[r], __shfl_xor(mx[r], off));

            int grow = 0;
#pragma unroll
            for (int r = 0; r < 4; ++r) grow |= (mx[r] > mrow[r]) ? 1 : 0;
            if (__any(grow)) {
#pragma unroll
                for (int r = 0; r < 4; ++r) {
                    float mn = fmaxf(mrow[r], mx[r]);
                    float al = exp2f(mrow[r] - mn);
                    mrow[r] = mn;
                    lpart[r] *= al;
#pragma unroll
                    for (int dt = 0; dt < 8; ++dt) o[dt][r] *= al;
                }
            }
            float p0[4], p1[4];
#pragma unroll
            for (int r = 0; r < 4; ++r) {
                p0[r] = exp2f(s0[r] - mrow[r]);
                p1[r] = exp2f(s1[r] - mrow[r]);
                lpart[r] += p0[r] + p1[r];
            }
#pragma unroll
            for (int r = 0; r < 4; ++r) {
                pl[((quad << 2) + r) * 40 + l16]      = f2bf(p0[r]);
                pl[((quad << 2) + r) * 40 + 16 + l16] = f2bf(p1[r]);
            }
            bh8 pa = *(const bh8*)(pl + l16 * 40 + (quad << 3));
            __builtin_amdgcn_s_setprio(1);
#pragma unroll
            for (int dt = 0; dt < 8; ++dt) {
                bh8 v = *(const bh8*)(vb + ((dt << 4) + l16) * 40 + (quad << 3));
                o[dt] = __builtin_amdgcn_mfma_f32_16x16x32_bf16(pa, v, o[dt], 0, 0, 0);
            }
            __builtin_amdgcn_s_setprio(0);

            if (pf) {
                u16* kd = kdst + (p ^ 1) * (32 * 136);
                u16* vd = vdst + (p ^ 1) * (128 * 40);
                *(uint4*)kd = pk0; *(uint4*)(kd + 8) = pk1;
                *(uint4*)vd = pv0; *(uint4*)(vd + 8) = pv1;
            }
            __syncthreads();
            p ^= 1;
        }
    }

#pragma unroll
    for (int off = 1; off <= 8; off <<= 1)
#pragma unroll
        for (int r = 0; r < 4; ++r) lpart[r] += __shfl_xor(lpart[r], off);

    if (mode == 0) {
        float inv[4];
#pragma unroll
        for (int r = 0; r < 4; ++r) inv[r] = 1.0f / lpart[r];
#pragma unroll
        for (int dt = 0; dt < 8; ++dt) {
#pragma unroll
            for (int r = 0; r < 4; ++r) {
                int row = sb + (quad << 2) + r;
                int col = (h << 7) + (dt << 4) + l16;
                Out[(size_t)row * D_TOT + col] = o[dt][r] * inv[r];
            }
        }
    } else {
        const size_t cb = ((size_t)ch * NH + h) * S_TOT;
#pragma unroll
        for (int dt = 0; dt < 8; ++dt) {
#pragma unroll
            for (int r = 0; r < 4; ++r) {
                int row = sb + (quad << 2) + r;
                Opart[(cb + row) * 128 + (dt << 4) + l16] = o[dt][r];
            }
        }
        if (l16 == 0) {
#pragma unroll
            for (int r = 0; r < 4; ++r) {
                int row = sb + (quad << 2) + r;
                Ml[cb + row] = (float2){mrow[r], lpart[r]};
            }
        }
    }
}

// ---------------- merge: Out = (Σ_c w_c O_c)/(Σ_c w_c l_c) + ipo ----------------
__global__ __launch_bounds__(256)
void merge_k(const float* __restrict__ Opart, const float2* __restrict__ Ml,
             const float* __restrict__ ipo, float* __restrict__ Out)
{
    int g = blockIdx.x * 4 + (threadIdx.x >> 6);   // (h,s) row id
    int lane = threadIdx.x & 63;
    int h = g / S_TOT;
    int s = g - h * S_TOT;
    float m[KS], l[KS];
#pragma unroll
    for (int c = 0; c < KS; ++c) {
        float2 ml = Ml[((size_t)c * NH + h) * S_TOT + s];
        m[c] = ml.x; l[c] = ml.y;
    }
    float M = m[0];
#pragma unroll
    for (int c = 1; c < KS; ++c) M = fmaxf(M, m[c]);
    float w[KS], lt = 0.f;
#pragma unroll
    for (int c = 0; c < KS; ++c) { w[c] = exp2f(m[c] - M); lt += w[c] * l[c]; }
    float inv = 1.0f / lt;
    float ax = 0.f, ay = 0.f;
#pragma unroll
    for (int c = 0; c < KS; ++c) {
        const float2 ov = *(const float2*)&Opart[(((size_t)c * NH + h) * S_TOT + s) * 128 + (lane << 1)];
        ax += w[c] * ov.x; ay += w[c] * ov.y;
    }
    size_t oidx = (size_t)s * D_TOT + (h << 7) + (lane << 1);
    float2 ip = *(const float2*)&ipo[oidx];
    float2 res = {ax * inv + ip.x, ay * inv + ip.y};
    *(float2*)&Out[oidx] = res;
}

// ---------------- workspace layout (byte offsets); ws >= 215 MB verified ----------------
// Phase A: conv writes xb/Wb. Phase B: GEMMs read xb/Wb, write qf/kf/vf (+kipf/vipf, t1).
// Phase C: norm/transpose read f32, write Qb/Kb/Vt/Kipb/Vipt (over dead xb/Wb).
// Phase D: attn writes opart (over dead qf/kf/vf) + ml + ipo (over dead Wb tail).
static const u64 B_OP   = 0;           // f32 [3][24][2304][128] (phase D; over dead qf/kf/vf)
static const u64 B_QF   = 0;
static const u64 B_KF   = 28311552;
static const u64 B_VF   = 56623104;
static const u64 B_KIPF = 84934656;
static const u64 B_VIPF = 86507520;
static const u64 B_T1   = 88080384;
static const u64 B_XB   = 88473600;    // bf16 [2304][3072] = 14,155,776 B (phase A-B; then Qb)
static const u64 B_WB   = 102629376;   // bf16 [3][3072][3072] = 56,623,104 B (phase A-B; then Kb/Vt/...)
static const u64 B_QB   = 88473600;    // bf16 [24][2304][128] (phase C+)
static const u64 B_KB   = 102629376;
static const u64 B_VT   = 116785152;
static const u64 B_KIPB = 130940928;
static const u64 B_VIPT = 131727360;
static const u64 B_ML   = 132513792;
static const u64 B_IPO  = 134217728;   // ends ~162.5 MB

extern "C" void kernel_launch(void* const* d_in, const int* in_sizes, int n_in,
                              void* d_out, int out_size, void* d_ws, size_t ws_size,
                              hipStream_t stream) {
    (void)in_sizes; (void)n_in; (void)out_size; (void)ws_size;
    const float* x    = (const float*)d_in[0];
    const float* img  = (const float*)d_in[1];
    const float* rc   = (const float*)d_in[2];
    const float* rsn  = (const float*)d_in[3];
    const float* Wq   = (const float*)d_in[4];
    const float* bq   = (const float*)d_in[5];
    const float* Wk   = (const float*)d_in[6];
    const float* bk   = (const float*)d_in[7];
    const float* Wv   = (const float*)d_in[8];
    const float* bv   = (const float*)d_in[9];
    const float* qdn  = (const float*)d_in[10];
    const float* qup  = (const float*)d_in[11];
    const float* kdn  = (const float*)d_in[12];
    const float* kup  = (const float*)d_in[13];
    const float* vdn  = (const float*)d_in[14];
    const float* vup  = (const float*)d_in[15];
    const float* nqw  = (const float*)d_in[16];
    const float* nkw  = (const float*)d_in[17];
    const float* Wkip = (const float*)d_in[18];
    const float* Wvip = (const float*)d_in[19];

    float*  qf   = (float*)((char*)d_ws + B_QF);
    float*  kf   = (float*)((char*)d_ws + B_KF);
    float*  vf   = (float*)((char*)d_ws + B_VF);
    float*  kipf = (float*)((char*)d_ws + B_KIPF);
    float*  vipf = (float*)((char*)d_ws + B_VIPF);
    float*  t1   = (float*)((char*)d_ws + B_T1);
    u16*    xb   = (u16*)((char*)d_ws + B_XB);
    u16*    Wb   = (u16*)((char*)d_ws + B_WB);
    u16*    Qb   = (u16*)((char*)d_ws + B_QB);
    u16*    Kb   = (u16*)((char*)d_ws + B_KB);
    u16*    Vt   = (u16*)((char*)d_ws + B_VT);
    u16*    Kipb = (u16*)((char*)d_ws + B_KIPB);
    u16*    Vipt = (u16*)((char*)d_ws + B_VIPT);
    float*  opart= (float*)((char*)d_ws + B_OP);
    float2* ml   = (float2*)((char*)d_ws + B_ML);
    float*  ipo  = (float*)((char*)d_ws + B_IPO);
    float*  outf = (float*)d_out;

    const float QSCALE = 0.08838834764831845f * 1.4426950408889634f;  // 1/sqrt(128) * log2(e)

    hipMemsetAsync((char*)d_ws + B_KIPF, 0, 2 * 1572864, stream);

    // 0) bulk f32->bf16: x and the three QKV weights
    conv_bf16_k<<<dim3(1152, 4), dim3(256), 0, stream>>>(
        x, xb, 884736,
        Wq, Wb, Wk, Wb + (size_t)D_TOT * D_TOT, Wv, Wb + 2 * (size_t)D_TOT * D_TOT, 1179648);

    // 1) QKV projections fused, bf16 inputs + global_load_lds staging
    gemm_qkv_bf16_k<<<dim3(18, 24, 3), dim3(256), 0, stream>>>(xb, Wb, bq, bk, bv, qf, kf, vf);

    // 2) LoRA: down fused (bf16 x), then up fused (+= into rows 2048..2303)
    lora_down_k<<<dim3(32, 3), dim3(256), 0, stream>>>(xb, qdn, kdn, vdn, t1);
    gemm_loraup_k<<<dim3(2, 24, 3), dim3(256), 0, stream>>>(t1, qup, kup, vup, qf, kf, vf);

    // 3) IP projections fused
    gemm_ip_k<<<dim3(1, 24, 16), dim3(256), 0, stream>>>(img, Wkip, Wvip, kipf, vipf);

    // 4) norm (+rope) -> head-major bf16 (Q pre-scaled); V transposes
    norm_qk_k<<<dim3(13824, 2), dim3(256), 0, stream>>>(qf, kf, nqw, nkw, rc, rsn, Qb, Kb, QSCALE);
    norm_ip_k<<<dim3(768), dim3(256), 0, stream>>>(kipf, Kipb);
    transpose_v_k<<<dim3(36, 24), dim3(256), 0, stream>>>(vf, Vt, S_TOT);
    transpose_v_k<<<dim3(2, 24),  dim3(256), 0, stream>>>(vipf, Vipt, TIP);

    // 5) attention: main split-K (2592 blocks, partial store), IP direct (864), merge
    attn_k<<<dim3(2592), dim3(256), 0, stream>>>(Qb, Kb, Vt, nullptr, opart, ml, S_TOT, 64, 24, 1, 36, 2592);
    attn_k<<<dim3(864),  dim3(256), 0, stream>>>(Qb, Kipb, Vipt, ipo, nullptr, nullptr, TIP, 0, 4, 0, 36, 864);
    merge_k<<<dim3(13824), dim3(256), 0, stream>>>(opart, ml, ipo, outf);
}